// Round 2
// baseline (1108.625 us; speedup 1.0000x reference)
//
#include <hip/hip_runtime.h>

typedef unsigned short u16;
typedef unsigned int u32;
typedef __bf16 bf16x8 __attribute__((ext_vector_type(8)));
typedef float f32x4 __attribute__((ext_vector_type(4)));

#define MFMA16(a, b, c) __builtin_amdgcn_mfma_f32_16x16x32_bf16(a, b, c, 0, 0, 0)

__device__ __forceinline__ u16 f2bf(float f) {
  u32 u = __builtin_bit_cast(u32, f);
  u32 r = u + 0x7fffu + ((u >> 16) & 1u);
  return (u16)(r >> 16);
}

__device__ __forceinline__ uint4 cvt8(const float4& a, const float4& b) {
  union { u16 h[8]; uint4 q; } u;
  u.h[0] = f2bf(a.x); u.h[1] = f2bf(a.y); u.h[2] = f2bf(a.z); u.h[3] = f2bf(a.w);
  u.h[4] = f2bf(b.x); u.h[5] = f2bf(b.y); u.h[6] = f2bf(b.z); u.h[7] = f2bf(b.w);
  return u.q;
}

// async global->LDS, 16B per lane; lds dst is wave-uniform base + lane*16
__device__ __forceinline__ void gload16(const u16* g, u16* l) {
  __builtin_amdgcn_global_load_lds(
      (const __attribute__((address_space(1))) u32*)g,
      (__attribute__((address_space(3))) u32*)l, 16, 0, 0);
}

// ---------------------------------------------------------------------------
// 128x128-tile bf16 MFMA GEMM, BK=32.
// ASRC 0: 4-buffer ring, prefetch depth 3, COUNTED vmcnt (never 0 in-loop),
//         raw s_barrier (no compiler vmcnt(0) drain). Per wave each tile is
//         4 global_load_lds ops -> steady-state wait vmcnt(8) = tile t landed,
//         t+1..t+3 in flight. Order per iter: waitcnt -> s_barrier -> mem
//         fence -> issue tile t+3 -> compute tile t. Buffer-reuse distance 4
//         > (barrier skew 1 + depth 3) => race-free.
// ASRC 2: A f32 convert-in-staging (adapter down), proven 2-buffer path.
// 1-D swizzled grid: groups of 32 M-blocks x all N-blocks for L2 locality.
// C = A(MxK, lda) * W(NxK, ldb)^T, fused epilogues.
// MODE 0: +bias, store bf16               (qkv)
// MODE 1: +bias +aux0(x f32), store f32   (out_proj -> x1 in d_out)
// MODE 2: +bias, relu, *gates, bf16       (adapter down -> hg)
// MODE 3: outF += 0.1*(acc + gb)          (adapter up -> y into d_out)
// MODE 4: +bias, QuickGELU, bf16          (c_fc -> h2)
// MODE 5: outF += acc (+bias if given)    (c_proj into d_out)
// ---------------------------------------------------------------------------
template <int MODE, int ASRC>
__global__ __launch_bounds__(256) void gemm_k(
    const void* __restrict__ Av, int lda,
    const u16* __restrict__ W, int ldb,
    const float* __restrict__ bias, const float* __restrict__ aux0,
    float* __restrict__ outF, u16* __restrict__ outB, int N, int K)
{
  constexpr int NBUF = (ASRC == 0) ? 4 : 2;
  __shared__ u16 As[NBUF][128 * 32];
  __shared__ u16 Bs[NBUF][128 * 32];
  const int tid = threadIdx.x;
  // swizzle: group g spans 32 consecutive M-blocks x all nxb N-blocks
  const int nxb = gridDim.x >> 7;         // N / 128
  const int gsz = nxb << 5;               // 32 * nxb
  const int g = blockIdx.x / gsz;
  const int rem = blockIdx.x - g * gsz;
  const int m0 = ((g << 5) + (rem & 31)) * 128;
  const int n0 = (rem >> 5) * 128;
  const int w = tid >> 6, lane = tid & 63, lr = lane & 15, quad = lane >> 4;
  const int wm = (w >> 1) * 64, wn = (w & 1) * 64;

  f32x4 acc[4][4];
  #pragma unroll
  for (int i = 0; i < 4; i++)
    #pragma unroll
    for (int j = 0; j < 4; j++)
      #pragma unroll
      for (int r = 0; r < 4; r++) acc[i][j][r] = 0.f;

  const int srow = w * 32 + (lane >> 2);
  const int scol = (lane & 3) * 8;
  const u16* gB0 = W + (long)(n0 + srow) * ldb + scol;
  const u16* gB1 = gB0 + (long)16 * ldb;
  const int lo = w * 1024;                // wave-uniform LDS offset (u16 units)

  const u16* gA0 = nullptr; const u16* gA1 = nullptr;
  const float* F1 = nullptr; const float* F2 = nullptr;
  const int r0 = tid >> 2, ch0 = (tid & 3) * 8;
  if constexpr (ASRC == 0) {
    gA0 = (const u16*)Av + (long)(m0 + srow) * lda + scol;
    gA1 = gA0 + (long)16 * lda;
  } else {
    F1 = (const float*)Av + (long)(m0 + r0) * lda + ch0;
    F2 = (const float*)Av + (long)(m0 + r0 + 64) * lda + ch0;
  }

  auto compute_tile = [&](const u16* Asc, const u16* Bsc) {
    bf16x8 bfr[4];
    #pragma unroll
    for (int j = 0; j < 4; j++)
      bfr[j] = *(const bf16x8*)&Bsc[(wn + j * 16 + lr) * 32 + quad * 8];
    #pragma unroll
    for (int i = 0; i < 4; i++) {
      bf16x8 af = *(const bf16x8*)&Asc[(wm + i * 16 + lr) * 32 + quad * 8];
      #pragma unroll
      for (int j = 0; j < 4; j++)
        acc[i][j] = MFMA16(af, bfr[j], acc[i][j]);
    }
  };

  if constexpr (ASRC == 0) {
    const int nt = K >> 5;  // >= 16 for all call sites
    // prologue: stage tiles 0..2 into bufs 0..2 (12 loads/wave in flight)
    #pragma unroll
    for (int p = 0; p < 3; p++) {
      const int kk = p * 32;
      gload16(gA0 + kk, &As[p][lo]);
      gload16(gA1 + kk, &As[p][lo + 512]);
      gload16(gB0 + kk, &Bs[p][lo]);
      gload16(gB1 + kk, &Bs[p][lo + 512]);
    }
    for (int t = 0; t < nt; t++) {
      // counted wait: tile t's 4 loads retired (vmcnt retires in order);
      // deeper tiles stay in flight ACROSS the barrier (T4).
      if (t < nt - 2)      asm volatile("s_waitcnt vmcnt(8)" ::: "memory");
      else if (t < nt - 1) asm volatile("s_waitcnt vmcnt(4)" ::: "memory");
      else                 asm volatile("s_waitcnt vmcnt(0)" ::: "memory");
      __builtin_amdgcn_s_barrier();
      // fence: s.barrier is NoMem in LLVM — pin all LDS reads / DMA issues
      // below the barrier so no wave touches buffers early.
      asm volatile("" ::: "memory");
      const int tp = t + 3;
      if (tp < nt) {
        const int kn = tp * 32;
        u16* a = As[tp & 3];
        u16* b = Bs[tp & 3];
        gload16(gA0 + kn, a + lo);
        gload16(gA1 + kn, a + lo + 512);
        gload16(gB0 + kn, b + lo);
        gload16(gB1 + kn, b + lo + 512);
      }
      compute_tile(As[t & 3], Bs[t & 3]);
    }
  } else {
    // ---------------- ASRC==2: proven 2-buffer __syncthreads path ----------
    int cur = 0;
    {
      float4 p0 = *(const float4*)(F1);
      float4 p1 = *(const float4*)(F1 + 4);
      float4 q0 = *(const float4*)(F2);
      float4 q1 = *(const float4*)(F2 + 4);
      gload16(gB0, &Bs[0][lo]);
      gload16(gB1, &Bs[0][lo + 512]);
      *(uint4*)&As[0][r0 * 32 + ch0] = cvt8(p0, p1);
      *(uint4*)&As[0][(r0 + 64) * 32 + ch0] = cvt8(q0, q1);
    }
    __syncthreads();
    for (int k0 = 0; k0 < K; k0 += 32) {
      const int kn = k0 + 32;
      const bool more = kn < K;
      float4 p0, p1, q0, q1;
      if (more) {
        p0 = *(const float4*)(F1 + kn);
        p1 = *(const float4*)(F1 + kn + 4);
        q0 = *(const float4*)(F2 + kn);
        q1 = *(const float4*)(F2 + kn + 4);
        gload16(gB0 + kn, &Bs[cur ^ 1][lo]);
        gload16(gB1 + kn, &Bs[cur ^ 1][lo + 512]);
      }
      compute_tile(As[cur], Bs[cur]);
      if (more) {
        *(uint4*)&As[cur ^ 1][r0 * 32 + ch0] = cvt8(p0, p1);
        *(uint4*)&As[cur ^ 1][(r0 + 64) * 32 + ch0] = cvt8(q0, q1);
      }
      __syncthreads();
      cur ^= 1;
    }
  }

  #pragma unroll
  for (int i = 0; i < 4; i++) {
    #pragma unroll
    for (int j = 0; j < 4; j++) {
      #pragma unroll
      for (int r = 0; r < 4; r++) {
        const int gm = m0 + wm + i * 16 + quad * 4 + r;
        const int gn = n0 + wn + j * 16 + lr;
        const long oidx = (long)gm * N + gn;
        float v = acc[i][j][r];
        if constexpr (MODE == 0) {
          v += bias[gn];
          outB[oidx] = f2bf(v);
        } else if constexpr (MODE == 1) {
          v += bias[gn] + aux0[oidx];
          outF[oidx] = v;
        } else if constexpr (MODE == 2) {
          v += bias[gn];
          v = fmaxf(v, 0.f);
          float g2 = aux0[(gm & 63) * 8 + (gn >> 6)];
          outB[oidx] = f2bf(v * g2);
        } else if constexpr (MODE == 3) {
          outF[oidx] += 0.1f * (v + aux0[(gm & 63) * 1024 + gn]);
        } else if constexpr (MODE == 4) {
          v += bias[gn];
          float e = __expf(-1.702f * v);
          v = v * __builtin_amdgcn_rcpf(1.f + e);
          outB[oidx] = f2bf(v);
        } else {
          if (bias) v += bias[gn];
          outF[oidx] += v;
        }
      }
    }
  }
}

// ---------------------------------------------------------------------------
// Fused attention per (b,h): S=QK^T/8 -> softmax -> P*V; O overwrites q-slot.
// qkv: [tok=l*64+b][3072], q@+0, k@+1024, v@+2048, col h*64+d. LDS ~51KB.
// ---------------------------------------------------------------------------
__global__ __launch_bounds__(256) void attn_k(u16* __restrict__ qkv)
{
  __shared__ u16 Vt[64 * 264];
  __shared__ u16 Ps[32 * 264];
  __shared__ float rowstat[64];
  float* red = (float*)Ps;  // red's lifetime ends before Ps is written
  const int bh = blockIdx.x, b = bh >> 4, h = bh & 15;
  const int tid = threadIdx.x, w = tid >> 6, lane = tid & 63;
  const int lr = lane & 15, quad = lane >> 4;
  const long base = (long)b * 3072 + h * 64;

  for (int c = tid; c < 2048; c += 256) {
    int m = c >> 3, ch = (c & 7) * 8;
    uint4 vv = *(const uint4*)(qkv + (long)m * 196608 + base + 2048 + ch);
    const u16* s = (const u16*)&vv;
    #pragma unroll
    for (int t = 0; t < 8; t++) Vt[(ch + t) * 264 + m] = s[t];
  }
  __syncthreads();

  for (int qb = 0; qb < 4; qb++) {
    f32x4 acc[4][4];
    #pragma unroll
    for (int i = 0; i < 4; i++)
      #pragma unroll
      for (int j = 0; j < 4; j++)
        #pragma unroll
        for (int r = 0; r < 4; r++) acc[i][j][r] = 0.f;

    #pragma unroll
    for (int ks = 0; ks < 2; ks++) {
      bf16x8 bfr[4];
      #pragma unroll
      for (int j = 0; j < 4; j++) {
        int key = w * 64 + j * 16 + lr;
        bfr[j] = *(const bf16x8*)(qkv + (long)key * 196608 + base + 1024 + ks * 32 + quad * 8);
      }
      #pragma unroll
      for (int i = 0; i < 4; i++) {
        int gq = qb * 64 + i * 16 + lr;
        bf16x8 af = *(const bf16x8*)(qkv + (long)gq * 196608 + base + ks * 32 + quad * 8);
        #pragma unroll
        for (int j = 0; j < 4; j++)
          acc[i][j] = MFMA16(af, bfr[j], acc[i][j]);
      }
    }

    #pragma unroll
    for (int i = 0; i < 4; i++) {
      #pragma unroll
      for (int r = 0; r < 4; r++) {
        float m = -1e30f;
        #pragma unroll
        for (int j = 0; j < 4; j++) {
          float s = acc[i][j][r] * 0.125f;
          acc[i][j][r] = s;
          m = fmaxf(m, s);
        }
        #pragma unroll
        for (int off = 1; off < 16; off <<= 1) m = fmaxf(m, __shfl_xor(m, off));
        if (lr == 0) red[w * 64 + i * 16 + quad * 4 + r] = m;
      }
    }
    __syncthreads();
    if (tid < 64)
      rowstat[tid] = fmaxf(fmaxf(red[tid], red[64 + tid]),
                           fmaxf(red[128 + tid], red[192 + tid]));
    __syncthreads();

    #pragma unroll
    for (int i = 0; i < 4; i++) {
      #pragma unroll
      for (int r = 0; r < 4; r++) {
        float rm = rowstat[i * 16 + quad * 4 + r];
        float s = 0.f;
        #pragma unroll
        for (int j = 0; j < 4; j++) {
          float e = __expf(acc[i][j][r] - rm);
          acc[i][j][r] = e;
          s += e;
        }
        #pragma unroll
        for (int off = 1; off < 16; off <<= 1) s += __shfl_xor(s, off);
        if (lr == 0) red[w * 64 + i * 16 + quad * 4 + r] = s;
      }
    }
    __syncthreads();
    if (tid < 64)
      rowstat[tid] = red[tid] + red[64 + tid] + red[128 + tid] + red[192 + tid];
    __syncthreads();

    #pragma unroll
    for (int hf = 0; hf < 2; hf++) {
      #pragma unroll
      for (int ii = 0; ii < 2; ii++) {
        int i = hf * 2 + ii;
        #pragma unroll
        for (int r = 0; r < 4; r++) {
          int row = i * 16 + quad * 4 + r;
          float inv = 1.f / rowstat[row];
          #pragma unroll
          for (int j = 0; j < 4; j++)
            Ps[(row - hf * 32) * 264 + w * 64 + j * 16 + lr] =
                f2bf(acc[i][j][r] * inv);
        }
      }
      __syncthreads();
      f32x4 o[2];
      #pragma unroll
      for (int j2 = 0; j2 < 2; j2++)
        #pragma unroll
        for (int r = 0; r < 4; r++) o[j2][r] = 0.f;
      #pragma unroll
      for (int ks = 0; ks < 8; ks++) {
        bf16x8 af = *(const bf16x8*)&Ps[((w >> 1) * 16 + lr) * 264 + ks * 32 + quad * 8];
        #pragma unroll
        for (int j2 = 0; j2 < 2; j2++) {
          int j = (w & 1) * 2 + j2;
          bf16x8 bv = *(const bf16x8*)&Vt[(j * 16 + lr) * 264 + ks * 32 + quad * 8];
          o[j2] = MFMA16(af, bv, o[j2]);
        }
      }
      int l0 = qb * 64 + hf * 32 + (w >> 1) * 16 + quad * 4;
      #pragma unroll
      for (int j2 = 0; j2 < 2; j2++) {
        int j = (w & 1) * 2 + j2;
        #pragma unroll
        for (int r = 0; r < 4; r++)
          qkv[(long)(l0 + r) * 196608 + base + j * 16 + lr] = f2bf(o[j2][r]);
      }
      __syncthreads();
    }
  }
}

// --------------------------- LayerNorm (f32 -> bf16) -----------------------
__global__ __launch_bounds__(256) void ln_k(const float* __restrict__ x,
                                            const float* __restrict__ wt,
                                            const float* __restrict__ bs,
                                            u16* __restrict__ out)
{
  const int tok = blockIdx.x * 4 + (threadIdx.x >> 6);
  const int lane = threadIdx.x & 63;
  const float* xp = x + (long)tok * 1024;
  float4 v[4];
  float s = 0.f, s2 = 0.f;
  #pragma unroll
  for (int t = 0; t < 4; t++) {
    v[t] = *(const float4*)(xp + t * 256 + lane * 4);
    s += v[t].x + v[t].y + v[t].z + v[t].w;
    s2 += v[t].x * v[t].x + v[t].y * v[t].y + v[t].z * v[t].z + v[t].w * v[t].w;
  }
  #pragma unroll
  for (int off = 32; off >= 1; off >>= 1) {
    s += __shfl_xor(s, off);
    s2 += __shfl_xor(s2, off);
  }
  const float m = s * (1.f / 1024.f);
  const float rstd = rsqrtf(s2 * (1.f / 1024.f) - m * m + 1e-5f);
  u16* op = out + (long)tok * 1024;
  #pragma unroll
  for (int t = 0; t < 4; t++) {
    int d = t * 256 + lane * 4;
    float4 wv = *(const float4*)(wt + d);
    float4 bv = *(const float4*)(bs + d);
    union { u16 h[4]; uint2 q; } o;
    o.h[0] = f2bf((v[t].x - m) * rstd * wv.x + bv.x);
    o.h[1] = f2bf((v[t].y - m) * rstd * wv.y + bv.y);
    o.h[2] = f2bf((v[t].z - m) * rstd * wv.z + bv.z);
    o.h[3] = f2bf((v[t].w - m) * rstd * wv.w + bv.w);
    *(uint2*)(op + d) = o.q;
  }
}

// --------------------------- weight converts -------------------------------
__global__ void cvtk(const float* __restrict__ src, u16* __restrict__ dst, int n4)
{
  int i = blockIdx.x * 256 + threadIdx.x;
  if (i >= n4) return;
  float4 v = ((const float4*)src)[i];
  union { u16 h[4]; uint2 q; } o;
  o.h[0] = f2bf(v.x); o.h[1] = f2bf(v.y); o.h[2] = f2bf(v.z); o.h[3] = f2bf(v.w);
  ((uint2*)dst)[i] = o.q;
}

// dst[d*512 + e*64 + r] = up_w[(e*1024 + d)*64 + r]   (up_w is (E,D,R))
__global__ void wupk(const float* __restrict__ up_w, u16* __restrict__ dst)
{
  int i = blockIdx.x * 256 + threadIdx.x;  // 524288
  int r = i & 63, e = (i >> 6) & 7, d = i >> 9;
  dst[i] = f2bf(up_w[(e * 1024 + d) * 64 + r]);
}

// --------------------------- gating ----------------------------------------
__global__ __launch_bounds__(256) void gate_k(const float* __restrict__ x1,
                                              const float* __restrict__ wg,
                                              float* __restrict__ gates)
{
  const int wv = threadIdx.x >> 6, lane = threadIdx.x & 63;
  const int b = blockIdx.x * 4 + wv;
  const float* xp = x1 + (long)b * 1024;
  float lg[8];
  #pragma unroll
  for (int e = 0; e < 8; e++) lg[e] = 0.f;
  for (int i = 0; i < 16; i++) {
    int d = i * 64 + lane;
    float xv = xp[d];
    #pragma unroll
    for (int e = 0; e < 8; e++) lg[e] += xv * wg[d * 8 + e];
  }
  #pragma unroll
  for (int e = 0; e < 8; e++)
    #pragma unroll
    for (int off = 32; off >= 1; off >>= 1) lg[e] += __shfl_xor(lg[e], off);
  if (lane == 0) {
    int e1 = 0; float v1 = lg[0];
    #pragma unroll
    for (int e = 1; e < 8; e++) if (lg[e] > v1) { v1 = lg[e]; e1 = e; }
    int e2 = -1; float v2 = -1e30f;
    #pragma unroll
    for (int e = 0; e < 8; e++) if (e != e1 && lg[e] > v2) { v2 = lg[e]; e2 = e; }
    float ex = __expf(v2 - v1);
    float inv = 1.f / (1.f + ex);
    #pragma unroll
    for (int e = 0; e < 8; e++)
      gates[b * 8 + e] = (e == e1) ? inv : ((e == e2) ? ex * inv : 0.f);
  }
}

__global__ void moe_loss_k(const float* __restrict__ gates, float* __restrict__ out)
{
  if (threadIdx.x != 0) return;
  float imp[8], ld[8];
  for (int e = 0; e < 8; e++) { imp[e] = 0.f; ld[e] = 0.f; }
  for (int b = 0; b < 64; b++)
    for (int e = 0; e < 8; e++) {
      float g = gates[b * 8 + e];
      imp[e] += g;
      if (g > 0.f) ld[e] += 1.f;
    }
  float mi = 0.f, ml = 0.f;
  for (int e = 0; e < 8; e++) { mi += imp[e]; ml += ld[e]; }
  mi *= 0.125f; ml *= 0.125f;
  float vi = 0.f, vl = 0.f;
  for (int e = 0; e < 8; e++) {
    float a = imp[e] - mi; vi += a * a;
    float c = ld[e] - ml; vl += c * c;
  }
  vi *= (1.f / 7.f); vl *= (1.f / 7.f);
  out[0] = 0.01f * (vi / (mi * mi + 1e-10f) + vl / (ml * ml + 1e-10f));
}

// gb[b][d] = sum_e gates[b,e] * up_b[e,d]
__global__ __launch_bounds__(256) void gb_k(const float* __restrict__ gates,
                                            const float* __restrict__ up_b,
                                            float* __restrict__ gb)
{
  int b = blockIdx.x, d0 = threadIdx.x * 4;
  float g[8];
  #pragma unroll
  for (int e = 0; e < 8; e++) g[e] = gates[b * 8 + e];
  float s0 = 0, s1 = 0, s2 = 0, s3 = 0;
  #pragma unroll
  for (int e = 0; e < 8; e++) {
    float4 u = *(const float4*)(up_b + e * 1024 + d0);
    s0 += g[e] * u.x; s1 += g[e] * u.y; s2 += g[e] * u.z; s3 += g[e] * u.w;
  }
  float4 r; r.x = s0; r.y = s1; r.z = s2; r.w = s3;
  *(float4*)(gb + b * 1024 + d0) = r;
}

// ---------------------------------------------------------------------------
extern "C" void kernel_launch(void* const* d_in, const int* in_sizes, int n_in,
                              void* d_out, int out_size, void* d_ws, size_t ws_size,
                              hipStream_t stream)
{
  (void)in_sizes; (void)n_in; (void)out_size;
  const float* x      = (const float*)d_in[0];
  const float* ln1_w  = (const float*)d_in[1];
  const float* ln1_b  = (const float*)d_in[2];
  const float* in_w   = (const float*)d_in[3];
  const float* in_b   = (const float*)d_in[4];
  const float* out_w  = (const float*)d_in[5];
  const float* out_b  = (const float*)d_in[6];
  const float* ln2_w  = (const float*)d_in[7];
  const float* ln2_b  = (const float*)d_in[8];
  const float* fc_w   = (const float*)d_in[9];
  const float* fc_b   = (const float*)d_in[10];
  const float* pj_w   = (const float*)d_in[11];
  const float* pj_b   = (const float*)d_in[12];
  const float* w_gate = (const float*)d_in[13];
  const float* down_w = (const float*)d_in[14];
  const float* down_b = (const float*)d_in[15];
  const float* up_w   = (const float*)d_in[16];
  const float* up_b   = (const float*)d_in[17];
  float* out = (float*)d_out;
  char* ws = (char*)d_ws;

  // ws layout (base footprint ~115 MB, proven), lifetime-aliased
  u16* wb_in   = (u16*)(ws + 0);          // 6 MB   (dead after qkv gemm)
  u16* wb_out  = (u16*)(ws + 6291456);    // 2 MB   (dead after out_proj)
  u16* wb_down = (u16*)(ws + 8388608);    // 1 MB
  u16* wb_up   = (u16*)(ws + 9437184);    // 1 MB
  u16* wb_fc   = (u16*)(ws + 0);          // 8 MB   (aliases in/out, converted late)
  u16* wb_pj   = (u16*)(ws + 10485760);   // 8 MB
  float* gates = (float*)(ws + 19005440); // 2 KB
  float* gb    = (float*)(ws + 19007488); // 256 KB
  u16* qkv     = (u16*)(ws + 19269632);   // 96 MB  (dead after out_proj)
  u16* xln2    = (u16*)(ws + 19269632);   // 32 MB  (alias qkv[0:32M])
  u16* hg      = (u16*)(ws + 52824064);   // 16 MB  (alias qkv[32M:48M])
  u16* h2      = (u16*)(ws + 69601280);   // 32 MB chunked / 128 MB if ws allows
  // xln (LN1 output, bf16) lives in d_out until out_proj overwrites it
  u16* xln = (u16*)d_out;

  const bool big = ws_size >= (size_t)203819008;  // 69601280 + 128 MB

  // phase-1 weight converts
  cvtk<<<3072, 256, 0, stream>>>(in_w, wb_in, 786432);
  cvtk<<<1024, 256, 0, stream>>>(out_w, wb_out, 262144);
  cvtk<<<512, 256, 0, stream>>>(down_w, wb_down, 131072);
  wupk<<<2048, 256, 0, stream>>>(up_w, wb_up);

  // LN1 -> xln (bf16, in d_out); qkv = xln @ in_w^T + in_b
  ln_k<<<4096, 256, 0, stream>>>(x, ln1_w, ln1_b, xln);
  gemm_k<0, 0><<<24 * 128, 256, 0, stream>>>(
      xln, 1024, wb_in, 1024, in_b, nullptr, nullptr, qkv, 3072, 1024);

  // fused attention; O overwrites q-slot of qkv
  attn_k<<<1024, 256, 0, stream>>>(qkv);

  // x1 = O @ out_w^T + out_b + x  -> d_out (f32)
  gemm_k<1, 0><<<8 * 128, 256, 0, stream>>>(
      qkv, 3072, wb_out, 1024, out_b, x, out, nullptr, 1024, 1024);

  // gating on x1 rows 0..63 (token 0 of each sequence)
  gate_k<<<16, 256, 0, stream>>>(out, w_gate, gates);
  moe_loss_k<<<1, 64, 0, stream>>>(gates, out + 16777216);
  gb_k<<<64, 256, 0, stream>>>(gates, up_b, gb);

  // LN2 must see pure x1 (before y accumulates into d_out)
  ln_k<<<4096, 256, 0, stream>>>(out, ln2_w, ln2_b, xln2);

  // adapter: down (relu, *gate) from f32 x1; up accumulates y into d_out
  gemm_k<2, 2><<<4 * 128, 256, 0, stream>>>(
      out, 1024, wb_down, 1024, down_b, gates, nullptr, hg, 512, 1024);
  gemm_k<3, 0><<<8 * 128, 256, 0, stream>>>(
      hg, 512, wb_up, 512, nullptr, gb, out, nullptr, 1024, 512);

  // phase-2 weight converts (overwrite dead phase-1 buffers)
  cvtk<<<4096, 256, 0, stream>>>(fc_w, wb_fc, 1048576);
  cvtk<<<4096, 256, 0, stream>>>(pj_w, wb_pj, 1048576);

  if (big) {
    // single-shot MLP: h2 = QuickGELU(xln2 @ fc_w^T + fc_b); out += h2 @ pj_w^T + pj_b
    gemm_k<4, 0><<<32 * 128, 256, 0, stream>>>(
        xln2, 1024, wb_fc, 1024, fc_b, nullptr, nullptr, h2, 4096, 1024);
    gemm_k<5, 0><<<8 * 128, 256, 0, stream>>>(
        h2, 4096, wb_pj, 4096, pj_b, nullptr, out, nullptr, 1024, 4096);
  } else {
    // 4 K-chunks (proven 115 MB footprint)
    for (int c = 0; c < 4; c++) {
      gemm_k<4, 0><<<8 * 128, 256, 0, stream>>>(
          xln2, 1024, wb_fc + (long)c * 1048576, 1024, fc_b + c * 1024,
          nullptr, nullptr, h2, 1024, 1024);
      gemm_k<5, 0><<<8 * 128, 256, 0, stream>>>(
          h2, 1024, wb_pj + c * 1024, 4096, (c == 0) ? pj_b : nullptr,
          nullptr, out, nullptr, 1024, 1024);
    }
  }
}

// Round 3
// 1048.029 us; speedup vs baseline: 1.0578x; 1.0578x over previous
//
#include <hip/hip_runtime.h>

typedef unsigned short u16;
typedef unsigned int u32;
typedef __bf16 bf16x8 __attribute__((ext_vector_type(8)));
typedef float f32x4 __attribute__((ext_vector_type(4)));

#define MFMA16(a, b, c) __builtin_amdgcn_mfma_f32_16x16x32_bf16(a, b, c, 0, 0, 0)

__device__ __forceinline__ u16 f2bf(float f) {
  u32 u = __builtin_bit_cast(u32, f);
  u32 r = u + 0x7fffu + ((u >> 16) & 1u);
  return (u16)(r >> 16);
}

__device__ __forceinline__ uint4 cvt8(const float4& a, const float4& b) {
  union { u16 h[8]; uint4 q; } u;
  u.h[0] = f2bf(a.x); u.h[1] = f2bf(a.y); u.h[2] = f2bf(a.z); u.h[3] = f2bf(a.w);
  u.h[4] = f2bf(b.x); u.h[5] = f2bf(b.y); u.h[6] = f2bf(b.z); u.h[7] = f2bf(b.w);
  return u.q;
}

// async global->LDS, 16B per lane; lds dst is wave-uniform base + lane*16
__device__ __forceinline__ void gload16(const u16* g, u16* l) {
  __builtin_amdgcn_global_load_lds(
      (const __attribute__((address_space(1))) u32*)g,
      (__attribute__((address_space(3))) u32*)l, 16, 0, 0);
}

// ---------------------------------------------------------------------------
// 256x256-tile bf16 MFMA GEMM, BK=32, 8 waves (512 thr), wave grid 2Mx4N,
// wave tile 128x64 (acc[8][4], 32 MFMA/step/wave). 4-buffer LDS ring (128KB),
// prefetch depth 3, COUNTED vmcnt (never 0 in-loop), raw s_barrier — sync
// discipline identical to the round-2-verified kernel.
// T2 swizzle: stage via pre-swizzled global col slot=(l&3)^((l>>3)&3) into
// LINEAR LDS; read at row*32 + (quad^((lr>>1)&3))*8 -> every ds_read_b128 is
// 2-way (free) instead of 8-way.
// Grid: 64 M-blocks x (N/256) N-blocks, 1-D swizzle groups of 16 M-blocks
// (stride-16 blockIdx => A-row sharers land on the same XCD).
// C = A(MxK, lda) * W(NxK, ldb)^T, fused epilogues:
// MODE 0: +bias, store bf16               (qkv)
// MODE 1: +bias +aux0(x f32), store f32   (out_proj -> x1 in d_out)
// MODE 3: outF += 0.1*(acc + gb)          (adapter up -> y into d_out)
// MODE 4: +bias, QuickGELU, bf16          (c_fc -> h2)
// MODE 5: outF += acc (+bias if given)    (c_proj into d_out)
// ---------------------------------------------------------------------------
template <int MODE>
__global__ __launch_bounds__(512, 2) void gemm256_k(
    const u16* __restrict__ A, int lda,
    const u16* __restrict__ W, int ldb,
    const float* __restrict__ bias, const float* __restrict__ aux0,
    float* __restrict__ outF, u16* __restrict__ outB, int N, int K)
{
  __shared__ u16 As[4][8192];   // 4 bufs x 256 rows x 32 cols
  __shared__ u16 Bs[4][8192];
  const int tid = threadIdx.x;
  const int nxb = N >> 8;
  const int gsz = nxb << 4;               // 16 M-blocks per group
  const int g = blockIdx.x / gsz;
  const int rem = blockIdx.x - g * gsz;
  const int m0 = ((g << 4) + (rem & 15)) * 256;
  const int n0 = (rem >> 4) * 256;
  const int w = tid >> 6, lane = tid & 63, lr = lane & 15, quad = lane >> 4;
  const int wr = (w >> 2) * 128, wc = (w & 3) * 64;

  f32x4 acc[8][4];
  #pragma unroll
  for (int i = 0; i < 8; i++)
    #pragma unroll
    for (int j = 0; j < 4; j++)
      #pragma unroll
      for (int r = 0; r < 4; r++) acc[i][j][r] = 0.f;

  // staging: thread covers stage-row sr (pass1: +128), 16B slot = lane&3.
  // source col-group pre-swizzled so LDS slot s of row r holds col-group
  // s ^ ((r>>1)&3)  (rule 21: linear LDS dest + inverse-swizzled source).
  const int sr = w * 16 + (lane >> 2);
  const int scol = ((lane & 3) ^ ((lane >> 3) & 3)) * 8;
  const u16* gA0 = A + (long)(m0 + sr) * lda + scol;
  const u16* gA1 = gA0 + (long)128 * lda;
  const u16* gB0 = W + (long)(n0 + sr) * ldb + scol;
  const u16* gB1 = gB0 + (long)128 * ldb;
  const int lo = w * 512;                 // wave-uniform LDS base (u16 units)
  // read-side swizzled slot offset (u16): frag rows are base+lr, base%16==0
  const int su = (quad ^ ((lr >> 1) & 3)) * 8;

  const int nt = K >> 5;                  // >= 16 at every call site
  // prologue: stage tiles 0..2 into bufs 0..2 (12 loads/thread in flight)
  #pragma unroll
  for (int p = 0; p < 3; p++) {
    const int kk = p * 32;
    gload16(gA0 + kk, &As[p][lo]);
    gload16(gA1 + kk, &As[p][4096 + lo]);
    gload16(gB0 + kk, &Bs[p][lo]);
    gload16(gB1 + kk, &Bs[p][4096 + lo]);
  }

  for (int t = 0; t < nt; t++) {
    // counted wait: tile t's 4 loads retired (per-wave, in-order); deeper
    // tiles stay in flight ACROSS the barrier. Barrier then publishes all
    // waves' tile-t staging to the whole block.
    if (t < nt - 2)      asm volatile("s_waitcnt vmcnt(8)" ::: "memory");
    else if (t < nt - 1) asm volatile("s_waitcnt vmcnt(4)" ::: "memory");
    else                 asm volatile("s_waitcnt vmcnt(0)" ::: "memory");
    __builtin_amdgcn_s_barrier();
    asm volatile("" ::: "memory");        // pin issue order below the barrier
    const int tp = t + 3;
    if (tp < nt) {
      const int kn = tp * 32;
      u16* a = As[tp & 3];
      u16* b = Bs[tp & 3];
      gload16(gA0 + kn, a + lo);
      gload16(gA1 + kn, a + 4096 + lo);
      gload16(gB0 + kn, b + lo);
      gload16(gB1 + kn, b + 4096 + lo);
    }
    const u16* Ab = As[t & 3];
    const u16* Bb = Bs[t & 3];
    bf16x8 bfr[4];
    #pragma unroll
    for (int j = 0; j < 4; j++)
      bfr[j] = *(const bf16x8*)&Bb[(wc + j * 16 + lr) * 32 + su];
    __builtin_amdgcn_s_setprio(1);
    #pragma unroll
    for (int i = 0; i < 8; i++) {
      bf16x8 af = *(const bf16x8*)&Ab[(wr + i * 16 + lr) * 32 + su];
      #pragma unroll
      for (int j = 0; j < 4; j++)
        acc[i][j] = MFMA16(af, bfr[j], acc[i][j]);
    }
    __builtin_amdgcn_s_setprio(0);
  }

  #pragma unroll
  for (int i = 0; i < 8; i++) {
    #pragma unroll
    for (int j = 0; j < 4; j++) {
      #pragma unroll
      for (int r = 0; r < 4; r++) {
        const int gm = m0 + wr + i * 16 + quad * 4 + r;
        const int gn = n0 + wc + j * 16 + lr;
        const long oidx = (long)gm * N + gn;
        float v = acc[i][j][r];
        if constexpr (MODE == 0) {
          v += bias[gn];
          outB[oidx] = f2bf(v);
        } else if constexpr (MODE == 1) {
          v += bias[gn] + aux0[oidx];
          outF[oidx] = v;
        } else if constexpr (MODE == 3) {
          outF[oidx] += 0.1f * (v + aux0[(gm & 63) * 1024 + gn]);
        } else if constexpr (MODE == 4) {
          v += bias[gn];
          float e = __expf(-1.702f * v);
          v = v * __builtin_amdgcn_rcpf(1.f + e);
          outB[oidx] = f2bf(v);
        } else {
          if (bias) v += bias[gn];
          outF[oidx] += v;
        }
      }
    }
  }
}

// ---------------------------------------------------------------------------
// Adapter-down GEMM (proven round-1/2 path): 128x128 tile, A f32 convert-in-
// staging, relu + gate epilogue. Small (N=512, K=1024) — not worth porting.
// ---------------------------------------------------------------------------
__global__ __launch_bounds__(256) void gemm_down_k(
    const float* __restrict__ Af, int lda,
    const u16* __restrict__ W, int ldb,
    const float* __restrict__ bias, const float* __restrict__ gates,
    u16* __restrict__ outB, int N, int K)
{
  __shared__ u16 As[2][128 * 32];
  __shared__ u16 Bs[2][128 * 32];
  const int tid = threadIdx.x;
  const int nxb = gridDim.x >> 7;
  const int gsz = nxb << 5;
  const int g = blockIdx.x / gsz;
  const int rem = blockIdx.x - g * gsz;
  const int m0 = ((g << 5) + (rem & 31)) * 128;
  const int n0 = (rem >> 5) * 128;
  const int w = tid >> 6, lane = tid & 63, lr = lane & 15, quad = lane >> 4;
  const int wm = (w >> 1) * 64, wn = (w & 1) * 64;

  f32x4 acc[4][4];
  #pragma unroll
  for (int i = 0; i < 4; i++)
    #pragma unroll
    for (int j = 0; j < 4; j++)
      #pragma unroll
      for (int r = 0; r < 4; r++) acc[i][j][r] = 0.f;

  const int srow = w * 32 + (lane >> 2);
  const int scol = (lane & 3) * 8;
  const u16* gB0 = W + (long)(n0 + srow) * ldb + scol;
  const u16* gB1 = gB0 + (long)16 * ldb;
  const int lo = w * 1024;
  const int r0 = tid >> 2, ch0 = (tid & 3) * 8;
  const float* F1 = Af + (long)(m0 + r0) * lda + ch0;
  const float* F2 = Af + (long)(m0 + r0 + 64) * lda + ch0;

  int cur = 0;
  {
    float4 p0 = *(const float4*)(F1);
    float4 p1 = *(const float4*)(F1 + 4);
    float4 q0 = *(const float4*)(F2);
    float4 q1 = *(const float4*)(F2 + 4);
    gload16(gB0, &Bs[0][lo]);
    gload16(gB1, &Bs[0][lo + 512]);
    *(uint4*)&As[0][r0 * 32 + ch0] = cvt8(p0, p1);
    *(uint4*)&As[0][(r0 + 64) * 32 + ch0] = cvt8(q0, q1);
  }
  __syncthreads();
  for (int k0 = 0; k0 < K; k0 += 32) {
    const int kn = k0 + 32;
    const bool more = kn < K;
    float4 p0, p1, q0, q1;
    if (more) {
      p0 = *(const float4*)(F1 + kn);
      p1 = *(const float4*)(F1 + kn + 4);
      q0 = *(const float4*)(F2 + kn);
      q1 = *(const float4*)(F2 + kn + 4);
      gload16(gB0 + kn, &Bs[cur ^ 1][lo]);
      gload16(gB1 + kn, &Bs[cur ^ 1][lo + 512]);
    }
    bf16x8 bfr[4];
    #pragma unroll
    for (int j = 0; j < 4; j++)
      bfr[j] = *(const bf16x8*)&Bs[cur][(wn + j * 16 + lr) * 32 + quad * 8];
    #pragma unroll
    for (int i = 0; i < 4; i++) {
      bf16x8 af = *(const bf16x8*)&As[cur][(wm + i * 16 + lr) * 32 + quad * 8];
      #pragma unroll
      for (int j = 0; j < 4; j++)
        acc[i][j] = MFMA16(af, bfr[j], acc[i][j]);
    }
    if (more) {
      *(uint4*)&As[cur ^ 1][r0 * 32 + ch0] = cvt8(p0, p1);
      *(uint4*)&As[cur ^ 1][(r0 + 64) * 32 + ch0] = cvt8(q0, q1);
    }
    __syncthreads();
    cur ^= 1;
  }

  #pragma unroll
  for (int i = 0; i < 4; i++) {
    #pragma unroll
    for (int j = 0; j < 4; j++) {
      #pragma unroll
      for (int r = 0; r < 4; r++) {
        const int gm = m0 + wm + i * 16 + quad * 4 + r;
        const int gn = n0 + wn + j * 16 + lr;
        float v = acc[i][j][r] + bias[gn];
        v = fmaxf(v, 0.f);
        float g2 = gates[(gm & 63) * 8 + (gn >> 6)];
        outB[(long)gm * N + gn] = f2bf(v * g2);
      }
    }
  }
}

// ---------------------------------------------------------------------------
// Fused attention per (b,h): S=QK^T/8 -> softmax -> P*V; O overwrites q-slot.
// qkv: [tok=l*64+b][3072], q@+0, k@+1024, v@+2048, col h*64+d. LDS ~51KB.
// ---------------------------------------------------------------------------
__global__ __launch_bounds__(256) void attn_k(u16* __restrict__ qkv)
{
  __shared__ u16 Vt[64 * 264];
  __shared__ u16 Ps[32 * 264];
  __shared__ float rowstat[64];
  float* red = (float*)Ps;  // red's lifetime ends before Ps is written
  const int bh = blockIdx.x, b = bh >> 4, h = bh & 15;
  const int tid = threadIdx.x, w = tid >> 6, lane = tid & 63;
  const int lr = lane & 15, quad = lane >> 4;
  const long base = (long)b * 3072 + h * 64;

  for (int c = tid; c < 2048; c += 256) {
    int m = c >> 3, ch = (c & 7) * 8;
    uint4 vv = *(const uint4*)(qkv + (long)m * 196608 + base + 2048 + ch);
    const u16* s = (const u16*)&vv;
    #pragma unroll
    for (int t = 0; t < 8; t++) Vt[(ch + t) * 264 + m] = s[t];
  }
  __syncthreads();

  for (int qb = 0; qb < 4; qb++) {
    f32x4 acc[4][4];
    #pragma unroll
    for (int i = 0; i < 4; i++)
      #pragma unroll
      for (int j = 0; j < 4; j++)
        #pragma unroll
        for (int r = 0; r < 4; r++) acc[i][j][r] = 0.f;

    #pragma unroll
    for (int ks = 0; ks < 2; ks++) {
      bf16x8 bfr[4];
      #pragma unroll
      for (int j = 0; j < 4; j++) {
        int key = w * 64 + j * 16 + lr;
        bfr[j] = *(const bf16x8*)(qkv + (long)key * 196608 + base + 1024 + ks * 32 + quad * 8);
      }
      #pragma unroll
      for (int i = 0; i < 4; i++) {
        int gq = qb * 64 + i * 16 + lr;
        bf16x8 af = *(const bf16x8*)(qkv + (long)gq * 196608 + base + ks * 32 + quad * 8);
        #pragma unroll
        for (int j = 0; j < 4; j++)
          acc[i][j] = MFMA16(af, bfr[j], acc[i][j]);
      }
    }

    #pragma unroll
    for (int i = 0; i < 4; i++) {
      #pragma unroll
      for (int r = 0; r < 4; r++) {
        float m = -1e30f;
        #pragma unroll
        for (int j = 0; j < 4; j++) {
          float s = acc[i][j][r] * 0.125f;
          acc[i][j][r] = s;
          m = fmaxf(m, s);
        }
        #pragma unroll
        for (int off = 1; off < 16; off <<= 1) m = fmaxf(m, __shfl_xor(m, off));
        if (lr == 0) red[w * 64 + i * 16 + quad * 4 + r] = m;
      }
    }
    __syncthreads();
    if (tid < 64)
      rowstat[tid] = fmaxf(fmaxf(red[tid], red[64 + tid]),
                           fmaxf(red[128 + tid], red[192 + tid]));
    __syncthreads();

    #pragma unroll
    for (int i = 0; i < 4; i++) {
      #pragma unroll
      for (int r = 0; r < 4; r++) {
        float rm = rowstat[i * 16 + quad * 4 + r];
        float s = 0.f;
        #pragma unroll
        for (int j = 0; j < 4; j++) {
          float e = __expf(acc[i][j][r] - rm);
          acc[i][j][r] = e;
          s += e;
        }
        #pragma unroll
        for (int off = 1; off < 16; off <<= 1) s += __shfl_xor(s, off);
        if (lr == 0) red[w * 64 + i * 16 + quad * 4 + r] = s;
      }
    }
    __syncthreads();
    if (tid < 64)
      rowstat[tid] = red[tid] + red[64 + tid] + red[128 + tid] + red[192 + tid];
    __syncthreads();

    #pragma unroll
    for (int hf = 0; hf < 2; hf++) {
      #pragma unroll
      for (int ii = 0; ii < 2; ii++) {
        int i = hf * 2 + ii;
        #pragma unroll
        for (int r = 0; r < 4; r++) {
          int row = i * 16 + quad * 4 + r;
          float inv = 1.f / rowstat[row];
          #pragma unroll
          for (int j = 0; j < 4; j++)
            Ps[(row - hf * 32) * 264 + w * 64 + j * 16 + lr] =
                f2bf(acc[i][j][r] * inv);
        }
      }
      __syncthreads();
      f32x4 o[2];
      #pragma unroll
      for (int j2 = 0; j2 < 2; j2++)
        #pragma unroll
        for (int r = 0; r < 4; r++) o[j2][r] = 0.f;
      #pragma unroll
      for (int ks = 0; ks < 8; ks++) {
        bf16x8 af = *(const bf16x8*)&Ps[((w >> 1) * 16 + lr) * 264 + ks * 32 + quad * 8];
        #pragma unroll
        for (int j2 = 0; j2 < 2; j2++) {
          int j = (w & 1) * 2 + j2;
          bf16x8 bv = *(const bf16x8*)&Vt[(j * 16 + lr) * 264 + ks * 32 + quad * 8];
          o[j2] = MFMA16(af, bv, o[j2]);
        }
      }
      int l0 = qb * 64 + hf * 32 + (w >> 1) * 16 + quad * 4;
      #pragma unroll
      for (int j2 = 0; j2 < 2; j2++) {
        int j = (w & 1) * 2 + j2;
        #pragma unroll
        for (int r = 0; r < 4; r++)
          qkv[(long)(l0 + r) * 196608 + base + j * 16 + lr] = f2bf(o[j2][r]);
      }
      __syncthreads();
    }
  }
}

// --------------------------- LayerNorm (f32 -> bf16) -----------------------
__global__ __launch_bounds__(256) void ln_k(const float* __restrict__ x,
                                            const float* __restrict__ wt,
                                            const float* __restrict__ bs,
                                            u16* __restrict__ out)
{
  const int tok = blockIdx.x * 4 + (threadIdx.x >> 6);
  const int lane = threadIdx.x & 63;
  const float* xp = x + (long)tok * 1024;
  float4 v[4];
  float s = 0.f, s2 = 0.f;
  #pragma unroll
  for (int t = 0; t < 4; t++) {
    v[t] = *(const float4*)(xp + t * 256 + lane * 4);
    s += v[t].x + v[t].y + v[t].z + v[t].w;
    s2 += v[t].x * v[t].x + v[t].y * v[t].y + v[t].z * v[t].z + v[t].w * v[t].w;
  }
  #pragma unroll
  for (int off = 32; off >= 1; off >>= 1) {
    s += __shfl_xor(s, off);
    s2 += __shfl_xor(s2, off);
  }
  const float m = s * (1.f / 1024.f);
  const float rstd = rsqrtf(s2 * (1.f / 1024.f) - m * m + 1e-5f);
  u16* op = out + (long)tok * 1024;
  #pragma unroll
  for (int t = 0; t < 4; t++) {
    int d = t * 256 + lane * 4;
    float4 wv = *(const float4*)(wt + d);
    float4 bv = *(const float4*)(bs + d);
    union { u16 h[4]; uint2 q; } o;
    o.h[0] = f2bf((v[t].x - m) * rstd * wv.x + bv.x);
    o.h[1] = f2bf((v[t].y - m) * rstd * wv.y + bv.y);
    o.h[2] = f2bf((v[t].z - m) * rstd * wv.z + bv.z);
    o.h[3] = f2bf((v[t].w - m) * rstd * wv.w + bv.w);
    *(uint2*)(op + d) = o.q;
  }
}

// --------------------------- weight converts -------------------------------
__global__ void cvtk(const float* __restrict__ src, u16* __restrict__ dst, int n4)
{
  int i = blockIdx.x * 256 + threadIdx.x;
  if (i >= n4) return;
  float4 v = ((const float4*)src)[i];
  union { u16 h[4]; uint2 q; } o;
  o.h[0] = f2bf(v.x); o.h[1] = f2bf(v.y); o.h[2] = f2bf(v.z); o.h[3] = f2bf(v.w);
  ((uint2*)dst)[i] = o.q;
}

// dst[d*512 + e*64 + r] = up_w[(e*1024 + d)*64 + r]   (up_w is (E,D,R))
__global__ void wupk(const float* __restrict__ up_w, u16* __restrict__ dst)
{
  int i = blockIdx.x * 256 + threadIdx.x;  // 524288
  int r = i & 63, e = (i >> 6) & 7, d = i >> 9;
  dst[i] = f2bf(up_w[(e * 1024 + d) * 64 + r]);
}

// --------------------------- gating ----------------------------------------
__global__ __launch_bounds__(256) void gate_k(const float* __restrict__ x1,
                                              const float* __restrict__ wg,
                                              float* __restrict__ gates)
{
  const int wv = threadIdx.x >> 6, lane = threadIdx.x & 63;
  const int b = blockIdx.x * 4 + wv;
  const float* xp = x1 + (long)b * 1024;
  float lg[8];
  #pragma unroll
  for (int e = 0; e < 8; e++) lg[e] = 0.f;
  for (int i = 0; i < 16; i++) {
    int d = i * 64 + lane;
    float xv = xp[d];
    #pragma unroll
    for (int e = 0; e < 8; e++) lg[e] += xv * wg[d * 8 + e];
  }
  #pragma unroll
  for (int e = 0; e < 8; e++)
    #pragma unroll
    for (int off = 32; off >= 1; off >>= 1) lg[e] += __shfl_xor(lg[e], off);
  if (lane == 0) {
    int e1 = 0; float v1 = lg[0];
    #pragma unroll
    for (int e = 1; e < 8; e++) if (lg[e] > v1) { v1 = lg[e]; e1 = e; }
    int e2 = -1; float v2 = -1e30f;
    #pragma unroll
    for (int e = 0; e < 8; e++) if (e != e1 && lg[e] > v2) { v2 = lg[e]; e2 = e; }
    float ex = __expf(v2 - v1);
    float inv = 1.f / (1.f + ex);
    #pragma unroll
    for (int e = 0; e < 8; e++)
      gates[b * 8 + e] = (e == e1) ? inv : ((e == e2) ? ex * inv : 0.f);
  }
}

__global__ void moe_loss_k(const float* __restrict__ gates, float* __restrict__ out)
{
  if (threadIdx.x != 0) return;
  float imp[8], ld[8];
  for (int e = 0; e < 8; e++) { imp[e] = 0.f; ld[e] = 0.f; }
  for (int b = 0; b < 64; b++)
    for (int e = 0; e < 8; e++) {
      float g = gates[b * 8 + e];
      imp[e] += g;
      if (g > 0.f) ld[e] += 1.f;
    }
  float mi = 0.f, ml = 0.f;
  for (int e = 0; e < 8; e++) { mi += imp[e]; ml += ld[e]; }
  mi *= 0.125f; ml *= 0.125f;
  float vi = 0.f, vl = 0.f;
  for (int e = 0; e < 8; e++) {
    float a = imp[e] - mi; vi += a * a;
    float c = ld[e] - ml; vl += c * c;
  }
  vi *= (1.f / 7.f); vl *= (1.f / 7.f);
  out[0] = 0.01f * (vi / (mi * mi + 1e-10f) + vl / (ml * ml + 1e-10f));
}

// gb[b][d] = sum_e gates[b,e] * up_b[e,d]
__global__ __launch_bounds__(256) void gb_k(const float* __restrict__ gates,
                                            const float* __restrict__ up_b,
                                            float* __restrict__ gb)
{
  int b = blockIdx.x, d0 = threadIdx.x * 4;
  float g[8];
  #pragma unroll
  for (int e = 0; e < 8; e++) g[e] = gates[b * 8 + e];
  float s0 = 0, s1 = 0, s2 = 0, s3 = 0;
  #pragma unroll
  for (int e = 0; e < 8; e++) {
    float4 u = *(const float4*)(up_b + e * 1024 + d0);
    s0 += g[e] * u.x; s1 += g[e] * u.y; s2 += g[e] * u.z; s3 += g[e] * u.w;
  }
  float4 r; r.x = s0; r.y = s1; r.z = s2; r.w = s3;
  *(float4*)(gb + b * 1024 + d0) = r;
}

// ---------------------------------------------------------------------------
extern "C" void kernel_launch(void* const* d_in, const int* in_sizes, int n_in,
                              void* d_out, int out_size, void* d_ws, size_t ws_size,
                              hipStream_t stream)
{
  (void)in_sizes; (void)n_in; (void)out_size;
  const float* x      = (const float*)d_in[0];
  const float* ln1_w  = (const float*)d_in[1];
  const float* ln1_b  = (const float*)d_in[2];
  const float* in_w   = (const float*)d_in[3];
  const float* in_b   = (const float*)d_in[4];
  const float* out_w  = (const float*)d_in[5];
  const float* out_b  = (const float*)d_in[6];
  const float* ln2_w  = (const float*)d_in[7];
  const float* ln2_b  = (const float*)d_in[8];
  const float* fc_w   = (const float*)d_in[9];
  const float* fc_b   = (const float*)d_in[10];
  const float* pj_w   = (const float*)d_in[11];
  const float* pj_b   = (const float*)d_in[12];
  const float* w_gate = (const float*)d_in[13];
  const float* down_w = (const float*)d_in[14];
  const float* down_b = (const float*)d_in[15];
  const float* up_w   = (const float*)d_in[16];
  const float* up_b   = (const float*)d_in[17];
  float* out = (float*)d_out;
  char* ws = (char*)d_ws;

  // ws layout (base footprint ~115 MB, proven), lifetime-aliased
  u16* wb_in   = (u16*)(ws + 0);          // 6 MB   (dead after qkv gemm)
  u16* wb_out  = (u16*)(ws + 6291456);    // 2 MB   (dead after out_proj)
  u16* wb_down = (u16*)(ws + 8388608);    // 1 MB
  u16* wb_up   = (u16*)(ws + 9437184);    // 1 MB
  u16* wb_fc   = (u16*)(ws + 0);          // 8 MB   (aliases in/out, converted late)
  u16* wb_pj   = (u16*)(ws + 10485760);   // 8 MB
  float* gates = (float*)(ws + 19005440); // 2 KB
  float* gb    = (float*)(ws + 19007488); // 256 KB
  u16* qkv     = (u16*)(ws + 19269632);   // 96 MB  (dead after out_proj)
  u16* xln2    = (u16*)(ws + 19269632);   // 32 MB  (alias qkv[0:32M])
  u16* hg      = (u16*)(ws + 52824064);   // 16 MB  (alias qkv[32M:48M])
  u16* h2      = (u16*)(ws + 69601280);   // 32 MB chunked / 128 MB if ws allows
  // xln (LN1 output, bf16) lives in d_out until out_proj overwrites it
  u16* xln = (u16*)d_out;

  const bool big = ws_size >= (size_t)203819008;  // 69601280 + 128 MB

  // phase-1 weight converts
  cvtk<<<3072, 256, 0, stream>>>(in_w, wb_in, 786432);
  cvtk<<<1024, 256, 0, stream>>>(out_w, wb_out, 262144);
  cvtk<<<512, 256, 0, stream>>>(down_w, wb_down, 131072);
  wupk<<<2048, 256, 0, stream>>>(up_w, wb_up);

  // LN1 -> xln (bf16, in d_out); qkv = xln @ in_w^T + in_b
  ln_k<<<4096, 256, 0, stream>>>(x, ln1_w, ln1_b, xln);
  gemm256_k<0><<<64 * 12, 512, 0, stream>>>(
      xln, 1024, wb_in, 1024, in_b, nullptr, nullptr, qkv, 3072, 1024);

  // fused attention; O overwrites q-slot of qkv
  attn_k<<<1024, 256, 0, stream>>>(qkv);

  // x1 = O @ out_w^T + out_b + x  -> d_out (f32)
  gemm256_k<1><<<64 * 4, 512, 0, stream>>>(
      qkv, 3072, wb_out, 1024, out_b, x, out, nullptr, 1024, 1024);

  // gating on x1 rows 0..63 (token 0 of each sequence)
  gate_k<<<16, 256, 0, stream>>>(out, w_gate, gates);
  moe_loss_k<<<1, 64, 0, stream>>>(gates, out + 16777216);
  gb_k<<<64, 256, 0, stream>>>(gates, up_b, gb);

  // LN2 must see pure x1 (before y accumulates into d_out)
  ln_k<<<4096, 256, 0, stream>>>(out, ln2_w, ln2_b, xln2);

  // adapter: down (relu, *gate) from f32 x1; up accumulates y into d_out
  gemm_down_k<<<4 * 128, 256, 0, stream>>>(
      out, 1024, wb_down, 1024, down_b, gates, hg, 512, 1024);
  gemm256_k<3><<<64 * 4, 512, 0, stream>>>(
      hg, 512, wb_up, 512, nullptr, gb, out, nullptr, 1024, 512);

  // phase-2 weight converts (overwrite dead phase-1 buffers)
  cvtk<<<4096, 256, 0, stream>>>(fc_w, wb_fc, 1048576);
  cvtk<<<4096, 256, 0, stream>>>(pj_w, wb_pj, 1048576);

  if (big) {
    // single-shot MLP: h2 = QuickGELU(xln2 @ fc_w^T + fc_b); out += h2 @ pj_w^T + pj_b
    gemm256_k<4><<<64 * 16, 512, 0, stream>>>(
        xln2, 1024, wb_fc, 1024, fc_b, nullptr, nullptr, h2, 4096, 1024);
    gemm256_k<5><<<64 * 4, 512, 0, stream>>>(
        h2, 4096, wb_pj, 4096, pj_b, nullptr, out, nullptr, 1024, 4096);
  } else {
    // 4 K-chunks (proven 115 MB footprint)
    for (int c = 0; c < 4; c++) {
      gemm256_k<4><<<64 * 4, 512, 0, stream>>>(
          xln2, 1024, wb_fc + (long)c * 1048576, 1024, fc_b + c * 1024,
          nullptr, nullptr, h2, 1024, 1024);
      gemm256_k<5><<<64 * 4, 512, 0, stream>>>(
          h2, 1024, wb_pj + c * 1024, 4096, (c == 0) ? pj_b : nullptr,
          nullptr, out, nullptr, 1024, 1024);
    }
  }
}

// Round 4
// 931.090 us; speedup vs baseline: 1.1907x; 1.1256x over previous
//
#include <hip/hip_runtime.h>

typedef unsigned short u16;
typedef unsigned int u32;
typedef __bf16 bf16x8 __attribute__((ext_vector_type(8)));
typedef float f32x4 __attribute__((ext_vector_type(4)));

#define MFMA16(a, b, c) __builtin_amdgcn_mfma_f32_16x16x32_bf16(a, b, c, 0, 0, 0)

__device__ __forceinline__ u16 f2bf(float f) {
  u32 u = __builtin_bit_cast(u32, f);
  u32 r = u + 0x7fffu + ((u >> 16) & 1u);
  return (u16)(r >> 16);
}

__device__ __forceinline__ uint4 cvt8(const float4& a, const float4& b) {
  union { u16 h[8]; uint4 q; } u;
  u.h[0] = f2bf(a.x); u.h[1] = f2bf(a.y); u.h[2] = f2bf(a.z); u.h[3] = f2bf(a.w);
  u.h[4] = f2bf(b.x); u.h[5] = f2bf(b.y); u.h[6] = f2bf(b.z); u.h[7] = f2bf(b.w);
  return u.q;
}

// async global->LDS, 16B per lane; lds dst is wave-uniform base + lane*16
__device__ __forceinline__ void gload16(const u16* g, u16* l) {
  __builtin_amdgcn_global_load_lds(
      (const __attribute__((address_space(1))) u32*)g,
      (__attribute__((address_space(3))) u32*)l, 16, 0, 0);
}

// memory-fenced raw barrier: fences pin LDS/VMEM ops to their phase; barrier
// itself is NoMem in LLVM so both sides need the fence.
#define BARF() do { asm volatile("" ::: "memory"); \
                    __builtin_amdgcn_s_barrier();  \
                    asm volatile("" ::: "memory"); } while (0)

// ---------------------------------------------------------------------------
// 256x256-tile bf16 MFMA GEMM, 8-PHASE schedule (T3+T4+T2+T5, m201 port).
// BK=64 K-tile, 8 waves (512 thr, 2Mx4N), wave tile 128x64, acc[8][4].
// LDS [2 buf][2 k-half][256][32] u16 = 128 KB; each (buf,khalf) A/B chunk is
// a DMA-linear 16 KB tile (2 gload16/wave), round-3-verified swizzle pair:
// stage col pre-swizzled  scol = ((l&3)^((l>>3)&3))*8  -> LDS[r][s] holds
// global slot s^((r>>1)&3);  read at  su = (quad^((lr>>1)&3))*8  -> 2-way
// bank access (free), measured 0 conflicts.
// Per K-tile: 8 phases, phase = (kstep, quadrant) with A/B frag holds
// (24 ds_read_b128/K-tile, minimal). One stage chunk issued at phases
// 0/2/4/6 (A-k0,B-k0,A-k1,B-k1 of NEXT tile -> opposite buffer). Counted
// vmcnt(4) at phases 3 and 7 ONLY (retires the 2 chunks needed 4-8 phases
// later; never drains in-loop). Race-free: all reads of a buffer are issued
// >=2 barriers before opposing DMA writes; waits precede publishing barriers.
// Grid: 64 M-blocks x (N/256), groups of 16 M-blocks (A-sharers same XCD).
// C = A(MxK, lda) * W(NxK, ldb)^T, fused epilogues:
// MODE 0: +bias, store bf16               (qkv)
// MODE 1: +bias +aux0(x f32), store f32   (out_proj -> x1 in d_out)
// MODE 3: outF += 0.1*(acc + gb)          (adapter up -> y into d_out)
// MODE 4: +bias, QuickGELU, bf16          (c_fc -> h2)
// MODE 5: outF += acc (+bias if given)    (c_proj into d_out)
// ---------------------------------------------------------------------------
template <int MODE>
__global__ __launch_bounds__(512, 2) void gemm256_k(
    const u16* __restrict__ A, int lda,
    const u16* __restrict__ W, int ldb,
    const float* __restrict__ bias, const float* __restrict__ aux0,
    float* __restrict__ outF, u16* __restrict__ outB, int N, int K)
{
  __shared__ u16 As[2][2][8192];   // [buf][khalf][256 rows x 32 cols]
  __shared__ u16 Bs[2][2][8192];
  const int tid = threadIdx.x;
  const int nxb = N >> 8;
  const int gsz = nxb << 4;               // 16 M-blocks per group
  const int g = blockIdx.x / gsz;
  const int rem = blockIdx.x - g * gsz;
  const int m0 = ((g << 4) + (rem & 15)) * 256;
  const int n0 = (rem >> 4) * 256;
  const int w = tid >> 6, lane = tid & 63, lr = lane & 15, quad = lane >> 4;
  const int wr = (w >> 2) * 128, wc = (w & 3) * 64;

  f32x4 acc[8][4];
  #pragma unroll
  for (int i = 0; i < 8; i++)
    #pragma unroll
    for (int j = 0; j < 4; j++)
      #pragma unroll
      for (int r = 0; r < 4; r++) acc[i][j][r] = 0.f;

  // staging addresses (verified round 3)
  const int sr = w * 16 + (lane >> 2);
  const int scol = ((lane & 3) ^ ((lane >> 3) & 3)) * 8;
  const u16* gA0 = A + (long)(m0 + sr) * lda + scol;
  const u16* gA1 = gA0 + (long)128 * lda;
  const u16* gB0 = W + (long)(n0 + sr) * ldb + scol;
  const u16* gB1 = gB0 + (long)128 * ldb;
  const int lo = w << 9;                  // wave-uniform LDS base (u16)
  const int su = (quad ^ ((lr >> 1) & 3)) * 8;   // read-side swizzled slot

  auto rdA = [&](bf16x8* af, const u16* tile, int ih) {
    #pragma unroll
    for (int i2 = 0; i2 < 4; i2++)
      af[i2] = *(const bf16x8*)&tile[(wr + ih * 64 + i2 * 16 + lr) * 32 + su];
  };
  auto rdB = [&](bf16x8* bfr, const u16* tile, int jh) {
    #pragma unroll
    for (int j2 = 0; j2 < 2; j2++)
      bfr[j2] = *(const bf16x8*)&tile[(wc + jh * 32 + j2 * 16 + lr) * 32 + su];
  };
  auto mm8 = [&](int ih, int jh, bf16x8* af, bf16x8* bfr) {
    __builtin_amdgcn_s_setprio(1);
    #pragma unroll
    for (int i2 = 0; i2 < 4; i2++)
      #pragma unroll
      for (int j2 = 0; j2 < 2; j2++)
        acc[ih * 4 + i2][jh * 2 + j2] =
            MFMA16(af[i2], bfr[j2], acc[ih * 4 + i2][jh * 2 + j2]);
    __builtin_amdgcn_s_setprio(0);
  };

  const int nt = K >> 6;                  // K-tiles of 64; >= 8 at all sites

  // prologue: stage K-tile 0 (4 chunks, 8 loads/wave), drain, publish
  gload16(gA0,      As[0][0] + lo); gload16(gA1,      As[0][0] + 4096 + lo);
  gload16(gB0,      Bs[0][0] + lo); gload16(gB1,      Bs[0][0] + 4096 + lo);
  gload16(gA0 + 32, As[0][1] + lo); gload16(gA1 + 32, As[0][1] + 4096 + lo);
  gload16(gB0 + 32, Bs[0][1] + lo); gload16(gB1 + 32, Bs[0][1] + 4096 + lo);
  asm volatile("s_waitcnt vmcnt(0)" ::: "memory");
  __syncthreads();

  for (int t = 0; t < nt; ++t) {
    const int cur = t & 1, nb = cur ^ 1;
    const bool more = (t + 1) < nt;
    const long kb = (long)(t + 1) * 64;
    const u16* A0 = As[cur][0]; const u16* A1 = As[cur][1];
    const u16* B0 = Bs[cur][0]; const u16* B1 = Bs[cur][1];
    bf16x8 af[4], b0[2], b1[2];
    // ---- p0: (k0, ih0, jh0) ----
    rdA(af, A0, 0); rdB(b0, B0, 0);
    if (more) { gload16(gA0 + kb, As[nb][0] + lo);
                gload16(gA1 + kb, As[nb][0] + 4096 + lo); }
    BARF(); mm8(0, 0, af, b0);
    // ---- p1: (k0, ih0, jh1) ----
    rdB(b1, B0, 1);
    BARF(); mm8(0, 1, af, b1);
    // ---- p2: (k0, ih1, jh1) ----
    rdA(af, A0, 1);
    if (more) { gload16(gB0 + kb, Bs[nb][0] + lo);
                gload16(gB1 + kb, Bs[nb][0] + 4096 + lo); }
    BARF(); mm8(1, 1, af, b1);
    // ---- p3: (k0, ih1, jh0) ----
    if (more) asm volatile("s_waitcnt vmcnt(4)" ::: "memory");
    else      asm volatile("s_waitcnt vmcnt(0)" ::: "memory");
    BARF(); mm8(1, 0, af, b0);
    // ---- p4: (k1, ih0, jh0) ----
    rdA(af, A1, 0); rdB(b0, B1, 0);
    if (more) { gload16(gA0 + kb + 32, As[nb][1] + lo);
                gload16(gA1 + kb + 32, As[nb][1] + 4096 + lo); }
    BARF(); mm8(0, 0, af, b0);
    // ---- p5: (k1, ih0, jh1) ----
    rdB(b1, B1, 1);
    BARF(); mm8(0, 1, af, b1);
    // ---- p6: (k1, ih1, jh1) ----
    rdA(af, A1, 1);
    if (more) { gload16(gB0 + kb + 32, Bs[nb][1] + lo);
                gload16(gB1 + kb + 32, Bs[nb][1] + 4096 + lo); }
    BARF(); mm8(1, 1, af, b1);
    // ---- p7: (k1, ih1, jh0) ----
    if (more) asm volatile("s_waitcnt vmcnt(4)" ::: "memory");
    BARF(); mm8(1, 0, af, b0);
  }

  #pragma unroll
  for (int i = 0; i < 8; i++) {
    #pragma unroll
    for (int j = 0; j < 4; j++) {
      #pragma unroll
      for (int r = 0; r < 4; r++) {
        const int gm = m0 + wr + i * 16 + quad * 4 + r;
        const int gn = n0 + wc + j * 16 + lr;
        const long oidx = (long)gm * N + gn;
        float v = acc[i][j][r];
        if constexpr (MODE == 0) {
          v += bias[gn];
          outB[oidx] = f2bf(v);
        } else if constexpr (MODE == 1) {
          v += bias[gn] + aux0[oidx];
          outF[oidx] = v;
        } else if constexpr (MODE == 3) {
          outF[oidx] += 0.1f * (v + aux0[(gm & 63) * 1024 + gn]);
        } else if constexpr (MODE == 4) {
          v += bias[gn];
          float e = __expf(-1.702f * v);
          v = v * __builtin_amdgcn_rcpf(1.f + e);
          outB[oidx] = f2bf(v);
        } else {
          if (bias) v += bias[gn];
          outF[oidx] += v;
        }
      }
    }
  }
}

// ---------------------------------------------------------------------------
// Adapter-down GEMM (proven round-1/2 path): 128x128 tile, A f32 convert-in-
// staging, relu + gate epilogue. Small (N=512, K=1024) — not worth porting.
// ---------------------------------------------------------------------------
__global__ __launch_bounds__(256) void gemm_down_k(
    const float* __restrict__ Af, int lda,
    const u16* __restrict__ W, int ldb,
    const float* __restrict__ bias, const float* __restrict__ gates,
    u16* __restrict__ outB, int N, int K)
{
  __shared__ u16 As[2][128 * 32];
  __shared__ u16 Bs[2][128 * 32];
  const int tid = threadIdx.x;
  const int nxb = gridDim.x >> 7;
  const int gsz = nxb << 5;
  const int g = blockIdx.x / gsz;
  const int rem = blockIdx.x - g * gsz;
  const int m0 = ((g << 5) + (rem & 31)) * 128;
  const int n0 = (rem >> 5) * 128;
  const int w = tid >> 6, lane = tid & 63, lr = lane & 15, quad = lane >> 4;
  const int wm = (w >> 1) * 64, wn = (w & 1) * 64;

  f32x4 acc[4][4];
  #pragma unroll
  for (int i = 0; i < 4; i++)
    #pragma unroll
    for (int j = 0; j < 4; j++)
      #pragma unroll
      for (int r = 0; r < 4; r++) acc[i][j][r] = 0.f;

  const int srow = w * 32 + (lane >> 2);
  const int scol = (lane & 3) * 8;
  const u16* gB0 = W + (long)(n0 + srow) * ldb + scol;
  const u16* gB1 = gB0 + (long)16 * ldb;
  const int lo = w * 1024;
  const int r0 = tid >> 2, ch0 = (tid & 3) * 8;
  const float* F1 = Af + (long)(m0 + r0) * lda + ch0;
  const float* F2 = Af + (long)(m0 + r0 + 64) * lda + ch0;

  int cur = 0;
  {
    float4 p0 = *(const float4*)(F1);
    float4 p1 = *(const float4*)(F1 + 4);
    float4 q0 = *(const float4*)(F2);
    float4 q1 = *(const float4*)(F2 + 4);
    gload16(gB0, &Bs[0][lo]);
    gload16(gB1, &Bs[0][lo + 512]);
    *(uint4*)&As[0][r0 * 32 + ch0] = cvt8(p0, p1);
    *(uint4*)&As[0][(r0 + 64) * 32 + ch0] = cvt8(q0, q1);
  }
  __syncthreads();
  for (int k0 = 0; k0 < K; k0 += 32) {
    const int kn = k0 + 32;
    const bool more = kn < K;
    float4 p0, p1, q0, q1;
    if (more) {
      p0 = *(const float4*)(F1 + kn);
      p1 = *(const float4*)(F1 + kn + 4);
      q0 = *(const float4*)(F2 + kn);
      q1 = *(const float4*)(F2 + kn + 4);
      gload16(gB0 + kn, &Bs[cur ^ 1][lo]);
      gload16(gB1 + kn, &Bs[cur ^ 1][lo + 512]);
    }
    bf16x8 bfr[4];
    #pragma unroll
    for (int j = 0; j < 4; j++)
      bfr[j] = *(const bf16x8*)&Bs[cur][(wn + j * 16 + lr) * 32 + quad * 8];
    #pragma unroll
    for (int i = 0; i < 4; i++) {
      bf16x8 af = *(const bf16x8*)&As[cur][(wm + i * 16 + lr) * 32 + quad * 8];
      #pragma unroll
      for (int j = 0; j < 4; j++)
        acc[i][j] = MFMA16(af, bfr[j], acc[i][j]);
    }
    if (more) {
      *(uint4*)&As[cur ^ 1][r0 * 32 + ch0] = cvt8(p0, p1);
      *(uint4*)&As[cur ^ 1][(r0 + 64) * 32 + ch0] = cvt8(q0, q1);
    }
    __syncthreads();
    cur ^= 1;
  }

  #pragma unroll
  for (int i = 0; i < 4; i++) {
    #pragma unroll
    for (int j = 0; j < 4; j++) {
      #pragma unroll
      for (int r = 0; r < 4; r++) {
        const int gm = m0 + wm + i * 16 + quad * 4 + r;
        const int gn = n0 + wn + j * 16 + lr;
        float v = acc[i][j][r] + bias[gn];
        v = fmaxf(v, 0.f);
        float g2 = gates[(gm & 63) * 8 + (gn >> 6)];
        outB[(long)gm * N + gn] = f2bf(v * g2);
      }
    }
  }
}

// ---------------------------------------------------------------------------
// Fused attention per (b,h): S=QK^T/8 -> softmax -> P*V; O overwrites q-slot.
// qkv: [tok=l*64+b][3072], q@+0, k@+1024, v@+2048, col h*64+d. LDS ~51KB.
// ---------------------------------------------------------------------------
__global__ __launch_bounds__(256) void attn_k(u16* __restrict__ qkv)
{
  __shared__ u16 Vt[64 * 264];
  __shared__ u16 Ps[32 * 264];
  __shared__ float rowstat[64];
  float* red = (float*)Ps;  // red's lifetime ends before Ps is written
  const int bh = blockIdx.x, b = bh >> 4, h = bh & 15;
  const int tid = threadIdx.x, w = tid >> 6, lane = tid & 63;
  const int lr = lane & 15, quad = lane >> 4;
  const long base = (long)b * 3072 + h * 64;

  for (int c = tid; c < 2048; c += 256) {
    int m = c >> 3, ch = (c & 7) * 8;
    uint4 vv = *(const uint4*)(qkv + (long)m * 196608 + base + 2048 + ch);
    const u16* s = (const u16*)&vv;
    #pragma unroll
    for (int t = 0; t < 8; t++) Vt[(ch + t) * 264 + m] = s[t];
  }
  __syncthreads();

  for (int qb = 0; qb < 4; qb++) {
    f32x4 acc[4][4];
    #pragma unroll
    for (int i = 0; i < 4; i++)
      #pragma unroll
      for (int j = 0; j < 4; j++)
        #pragma unroll
        for (int r = 0; r < 4; r++) acc[i][j][r] = 0.f;

    #pragma unroll
    for (int ks = 0; ks < 2; ks++) {
      bf16x8 bfr[4];
      #pragma unroll
      for (int j = 0; j < 4; j++) {
        int key = w * 64 + j * 16 + lr;
        bfr[j] = *(const bf16x8*)(qkv + (long)key * 196608 + base + 1024 + ks * 32 + quad * 8);
      }
      #pragma unroll
      for (int i = 0; i < 4; i++) {
        int gq = qb * 64 + i * 16 + lr;
        bf16x8 af = *(const bf16x8*)(qkv + (long)gq * 196608 + base + ks * 32 + quad * 8);
        #pragma unroll
        for (int j = 0; j < 4; j++)
          acc[i][j] = MFMA16(af, bfr[j], acc[i][j]);
      }
    }

    #pragma unroll
    for (int i = 0; i < 4; i++) {
      #pragma unroll
      for (int r = 0; r < 4; r++) {
        float m = -1e30f;
        #pragma unroll
        for (int j = 0; j < 4; j++) {
          float s = acc[i][j][r] * 0.125f;
          acc[i][j][r] = s;
          m = fmaxf(m, s);
        }
        #pragma unroll
        for (int off = 1; off < 16; off <<= 1) m = fmaxf(m, __shfl_xor(m, off));
        if (lr == 0) red[w * 64 + i * 16 + quad * 4 + r] = m;
      }
    }
    __syncthreads();
    if (tid < 64)
      rowstat[tid] = fmaxf(fmaxf(red[tid], red[64 + tid]),
                           fmaxf(red[128 + tid], red[192 + tid]));
    __syncthreads();

    #pragma unroll
    for (int i = 0; i < 4; i++) {
      #pragma unroll
      for (int r = 0; r < 4; r++) {
        float rm = rowstat[i * 16 + quad * 4 + r];
        float s = 0.f;
        #pragma unroll
        for (int j = 0; j < 4; j++) {
          float e = __expf(acc[i][j][r] - rm);
          acc[i][j][r] = e;
          s += e;
        }
        #pragma unroll
        for (int off = 1; off < 16; off <<= 1) s += __shfl_xor(s, off);
        if (lr == 0) red[w * 64 + i * 16 + quad * 4 + r] = s;
      }
    }
    __syncthreads();
    if (tid < 64)
      rowstat[tid] = red[tid] + red[64 + tid] + red[128 + tid] + red[192 + tid];
    __syncthreads();

    #pragma unroll
    for (int hf = 0; hf < 2; hf++) {
      #pragma unroll
      for (int ii = 0; ii < 2; ii++) {
        int i = hf * 2 + ii;
        #pragma unroll
        for (int r = 0; r < 4; r++) {
          int row = i * 16 + quad * 4 + r;
          float inv = 1.f / rowstat[row];
          #pragma unroll
          for (int j = 0; j < 4; j++)
            Ps[(row - hf * 32) * 264 + w * 64 + j * 16 + lr] =
                f2bf(acc[i][j][r] * inv);
        }
      }
      __syncthreads();
      f32x4 o[2];
      #pragma unroll
      for (int j2 = 0; j2 < 2; j2++)
        #pragma unroll
        for (int r = 0; r < 4; r++) o[j2][r] = 0.f;
      #pragma unroll
      for (int ks = 0; ks < 8; ks++) {
        bf16x8 af = *(const bf16x8*)&Ps[((w >> 1) * 16 + lr) * 264 + ks * 32 + quad * 8];
        #pragma unroll
        for (int j2 = 0; j2 < 2; j2++) {
          int j = (w & 1) * 2 + j2;
          bf16x8 bv = *(const bf16x8*)&Vt[(j * 16 + lr) * 264 + ks * 32 + quad * 8];
          o[j2] = MFMA16(af, bv, o[j2]);
        }
      }
      int l0 = qb * 64 + hf * 32 + (w >> 1) * 16 + quad * 4;
      #pragma unroll
      for (int j2 = 0; j2 < 2; j2++) {
        int j = (w & 1) * 2 + j2;
        #pragma unroll
        for (int r = 0; r < 4; r++)
          qkv[(long)(l0 + r) * 196608 + base + j * 16 + lr] = f2bf(o[j2][r]);
      }
      __syncthreads();
    }
  }
}

// --------------------------- LayerNorm (f32 -> bf16) -----------------------
__global__ __launch_bounds__(256) void ln_k(const float* __restrict__ x,
                                            const float* __restrict__ wt,
                                            const float* __restrict__ bs,
                                            u16* __restrict__ out)
{
  const int tok = blockIdx.x * 4 + (threadIdx.x >> 6);
  const int lane = threadIdx.x & 63;
  const float* xp = x + (long)tok * 1024;
  float4 v[4];
  float s = 0.f, s2 = 0.f;
  #pragma unroll
  for (int t = 0; t < 4; t++) {
    v[t] = *(const float4*)(xp + t * 256 + lane * 4);
    s += v[t].x + v[t].y + v[t].z + v[t].w;
    s2 += v[t].x * v[t].x + v[t].y * v[t].y + v[t].z * v[t].z + v[t].w * v[t].w;
  }
  #pragma unroll
  for (int off = 32; off >= 1; off >>= 1) {
    s += __shfl_xor(s, off);
    s2 += __shfl_xor(s2, off);
  }
  const float m = s * (1.f / 1024.f);
  const float rstd = rsqrtf(s2 * (1.f / 1024.f) - m * m + 1e-5f);
  u16* op = out + (long)tok * 1024;
  #pragma unroll
  for (int t = 0; t < 4; t++) {
    int d = t * 256 + lane * 4;
    float4 wv = *(const float4*)(wt + d);
    float4 bv = *(const float4*)(bs + d);
    union { u16 h[4]; uint2 q; } o;
    o.h[0] = f2bf((v[t].x - m) * rstd * wv.x + bv.x);
    o.h[1] = f2bf((v[t].y - m) * rstd * wv.y + bv.y);
    o.h[2] = f2bf((v[t].z - m) * rstd * wv.z + bv.z);
    o.h[3] = f2bf((v[t].w - m) * rstd * wv.w + bv.w);
    *(uint2*)(op + d) = o.q;
  }
}

// --------------------------- weight converts -------------------------------
__global__ void cvtk(const float* __restrict__ src, u16* __restrict__ dst, int n4)
{
  int i = blockIdx.x * 256 + threadIdx.x;
  if (i >= n4) return;
  float4 v = ((const float4*)src)[i];
  union { u16 h[4]; uint2 q; } o;
  o.h[0] = f2bf(v.x); o.h[1] = f2bf(v.y); o.h[2] = f2bf(v.z); o.h[3] = f2bf(v.w);
  ((uint2*)dst)[i] = o.q;
}

// dst[d*512 + e*64 + r] = up_w[(e*1024 + d)*64 + r]   (up_w is (E,D,R))
__global__ void wupk(const float* __restrict__ up_w, u16* __restrict__ dst)
{
  int i = blockIdx.x * 256 + threadIdx.x;  // 524288
  int r = i & 63, e = (i >> 6) & 7, d = i >> 9;
  dst[i] = f2bf(up_w[(e * 1024 + d) * 64 + r]);
}

// --------------------------- gating ----------------------------------------
__global__ __launch_bounds__(256) void gate_k(const float* __restrict__ x1,
                                              const float* __restrict__ wg,
                                              float* __restrict__ gates)
{
  const int wv = threadIdx.x >> 6, lane = threadIdx.x & 63;
  const int b = blockIdx.x * 4 + wv;
  const float* xp = x1 + (long)b * 1024;
  float lg[8];
  #pragma unroll
  for (int e = 0; e < 8; e++) lg[e] = 0.f;
  for (int i = 0; i < 16; i++) {
    int d = i * 64 + lane;
    float xv = xp[d];
    #pragma unroll
    for (int e = 0; e < 8; e++) lg[e] += xv * wg[d * 8 + e];
  }
  #pragma unroll
  for (int e = 0; e < 8; e++)
    #pragma unroll
    for (int off = 32; off >= 1; off >>= 1) lg[e] += __shfl_xor(lg[e], off);
  if (lane == 0) {
    int e1 = 0; float v1 = lg[0];
    #pragma unroll
    for (int e = 1; e < 8; e++) if (lg[e] > v1) { v1 = lg[e]; e1 = e; }
    int e2 = -1; float v2 = -1e30f;
    #pragma unroll
    for (int e = 0; e < 8; e++) if (e != e1 && lg[e] > v2) { v2 = lg[e]; e2 = e; }
    float ex = __expf(v2 - v1);
    float inv = 1.f / (1.f + ex);
    #pragma unroll
    for (int e = 0; e < 8; e++)
      gates[b * 8 + e] = (e == e1) ? inv : ((e == e2) ? ex * inv : 0.f);
  }
}

__global__ void moe_loss_k(const float* __restrict__ gates, float* __restrict__ out)
{
  if (threadIdx.x != 0) return;
  float imp[8], ld[8];
  for (int e = 0; e < 8; e++) { imp[e] = 0.f; ld[e] = 0.f; }
  for (int b = 0; b < 64; b++)
    for (int e = 0; e < 8; e++) {
      float g = gates[b * 8 + e];
      imp[e] += g;
      if (g > 0.f) ld[e] += 1.f;
    }
  float mi = 0.f, ml = 0.f;
  for (int e = 0; e < 8; e++) { mi += imp[e]; ml += ld[e]; }
  mi *= 0.125f; ml *= 0.125f;
  float vi = 0.f, vl = 0.f;
  for (int e = 0; e < 8; e++) {
    float a = imp[e] - mi; vi += a * a;
    float c = ld[e] - ml; vl += c * c;
  }
  vi *= (1.f / 7.f); vl *= (1.f / 7.f);
  out[0] = 0.01f * (vi / (mi * mi + 1e-10f) + vl / (ml * ml + 1e-10f));
}

// gb[b][d] = sum_e gates[b,e] * up_b[e,d]
__global__ __launch_bounds__(256) void gb_k(const float* __restrict__ gates,
                                            const float* __restrict__ up_b,
                                            float* __restrict__ gb)
{
  int b = blockIdx.x, d0 = threadIdx.x * 4;
  float g[8];
  #pragma unroll
  for (int e = 0; e < 8; e++) g[e] = gates[b * 8 + e];
  float s0 = 0, s1 = 0, s2 = 0, s3 = 0;
  #pragma unroll
  for (int e = 0; e < 8; e++) {
    float4 u = *(const float4*)(up_b + e * 1024 + d0);
    s0 += g[e] * u.x; s1 += g[e] * u.y; s2 += g[e] * u.z; s3 += g[e] * u.w;
  }
  float4 r; r.x = s0; r.y = s1; r.z = s2; r.w = s3;
  *(float4*)(gb + b * 1024 + d0) = r;
}

// ---------------------------------------------------------------------------
extern "C" void kernel_launch(void* const* d_in, const int* in_sizes, int n_in,
                              void* d_out, int out_size, void* d_ws, size_t ws_size,
                              hipStream_t stream)
{
  (void)in_sizes; (void)n_in; (void)out_size;
  const float* x      = (const float*)d_in[0];
  const float* ln1_w  = (const float*)d_in[1];
  const float* ln1_b  = (const float*)d_in[2];
  const float* in_w   = (const float*)d_in[3];
  const float* in_b   = (const float*)d_in[4];
  const float* out_w  = (const float*)d_in[5];
  const float* out_b  = (const float*)d_in[6];
  const float* ln2_w  = (const float*)d_in[7];
  const float* ln2_b  = (const float*)d_in[8];
  const float* fc_w   = (const float*)d_in[9];
  const float* fc_b   = (const float*)d_in[10];
  const float* pj_w   = (const float*)d_in[11];
  const float* pj_b   = (const float*)d_in[12];
  const float* w_gate = (const float*)d_in[13];
  const float* down_w = (const float*)d_in[14];
  const float* down_b = (const float*)d_in[15];
  const float* up_w   = (const float*)d_in[16];
  const float* up_b   = (const float*)d_in[17];
  float* out = (float*)d_out;
  char* ws = (char*)d_ws;

  // ws layout (base footprint ~115 MB, proven), lifetime-aliased
  u16* wb_in   = (u16*)(ws + 0);          // 6 MB   (dead after qkv gemm)
  u16* wb_out  = (u16*)(ws + 6291456);    // 2 MB   (dead after out_proj)
  u16* wb_down = (u16*)(ws + 8388608);    // 1 MB
  u16* wb_up   = (u16*)(ws + 9437184);    // 1 MB
  u16* wb_fc   = (u16*)(ws + 0);          // 8 MB   (aliases in/out, converted late)
  u16* wb_pj   = (u16*)(ws + 10485760);   // 8 MB
  float* gates = (float*)(ws + 19005440); // 2 KB
  float* gb    = (float*)(ws + 19007488); // 256 KB
  u16* qkv     = (u16*)(ws + 19269632);   // 96 MB  (dead after out_proj)
  u16* xln2    = (u16*)(ws + 19269632);   // 32 MB  (alias qkv[0:32M])
  u16* hg      = (u16*)(ws + 52824064);   // 16 MB  (alias qkv[32M:48M])
  u16* h2      = (u16*)(ws + 69601280);   // 32 MB chunked / 128 MB if ws allows
  // xln (LN1 output, bf16) lives in d_out until out_proj overwrites it
  u16* xln = (u16*)d_out;

  const bool big = ws_size >= (size_t)203819008;  // 69601280 + 128 MB

  // phase-1 weight converts
  cvtk<<<3072, 256, 0, stream>>>(in_w, wb_in, 786432);
  cvtk<<<1024, 256, 0, stream>>>(out_w, wb_out, 262144);
  cvtk<<<512, 256, 0, stream>>>(down_w, wb_down, 131072);
  wupk<<<2048, 256, 0, stream>>>(up_w, wb_up);

  // LN1 -> xln (bf16, in d_out); qkv = xln @ in_w^T + in_b
  ln_k<<<4096, 256, 0, stream>>>(x, ln1_w, ln1_b, xln);
  gemm256_k<0><<<64 * 12, 512, 0, stream>>>(
      xln, 1024, wb_in, 1024, in_b, nullptr, nullptr, qkv, 3072, 1024);

  // fused attention; O overwrites q-slot of qkv
  attn_k<<<1024, 256, 0, stream>>>(qkv);

  // x1 = O @ out_w^T + out_b + x  -> d_out (f32)
  gemm256_k<1><<<64 * 4, 512, 0, stream>>>(
      qkv, 3072, wb_out, 1024, out_b, x, out, nullptr, 1024, 1024);

  // gating on x1 rows 0..63 (token 0 of each sequence)
  gate_k<<<16, 256, 0, stream>>>(out, w_gate, gates);
  moe_loss_k<<<1, 64, 0, stream>>>(gates, out + 16777216);
  gb_k<<<64, 256, 0, stream>>>(gates, up_b, gb);

  // LN2 must see pure x1 (before y accumulates into d_out)
  ln_k<<<4096, 256, 0, stream>>>(out, ln2_w, ln2_b, xln2);

  // adapter: down (relu, *gate) from f32 x1; up accumulates y into d_out
  gemm_down_k<<<4 * 128, 256, 0, stream>>>(
      out, 1024, wb_down, 1024, down_b, gates, hg, 512, 1024);
  gemm256_k<3><<<64 * 4, 512, 0, stream>>>(
      hg, 512, wb_up, 512, nullptr, gb, out, nullptr, 1024, 512);

  // phase-2 weight converts (overwrite dead phase-1 buffers)
  cvtk<<<4096, 256, 0, stream>>>(fc_w, wb_fc, 1048576);
  cvtk<<<4096, 256, 0, stream>>>(pj_w, wb_pj, 1048576);

  if (big) {
    // single-shot MLP: h2 = QuickGELU(xln2 @ fc_w^T + fc_b); out += h2 @ pj_w^T + pj_b
    gemm256_k<4><<<64 * 16, 512, 0, stream>>>(
        xln2, 1024, wb_fc, 1024, fc_b, nullptr, nullptr, h2, 4096, 1024);
    gemm256_k<5><<<64 * 4, 512, 0, stream>>>(
        h2, 4096, wb_pj, 4096, pj_b, nullptr, out, nullptr, 1024, 4096);
  } else {
    // 4 K-chunks (proven 115 MB footprint)
    for (int c = 0; c < 4; c++) {
      gemm256_k<4><<<64 * 4, 512, 0, stream>>>(
          xln2, 1024, wb_fc + (long)c * 1048576, 1024, fc_b + c * 1024,
          nullptr, nullptr, h2, 1024, 1024);
      gemm256_k<5><<<64 * 4, 512, 0, stream>>>(
          h2, 1024, wb_pj + c * 1024, 4096, (c == 0) ? pj_b : nullptr,
          nullptr, out, nullptr, 1024, 1024);
    }
  }
}

// Round 5
// 894.803 us; speedup vs baseline: 1.2390x; 1.0406x over previous
//
#include <hip/hip_runtime.h>

typedef unsigned short u16;
typedef unsigned int u32;
typedef __bf16 bf16x8 __attribute__((ext_vector_type(8)));
typedef float f32x4 __attribute__((ext_vector_type(4)));

#define MFMA16(a, b, c) __builtin_amdgcn_mfma_f32_16x16x32_bf16(a, b, c, 0, 0, 0)

__device__ __forceinline__ u16 f2bf(float f) {
  u32 u = __builtin_bit_cast(u32, f);
  u32 r = u + 0x7fffu + ((u >> 16) & 1u);
  return (u16)(r >> 16);
}

__device__ __forceinline__ uint4 cvt8(const float4& a, const float4& b) {
  union { u16 h[8]; uint4 q; } u;
  u.h[0] = f2bf(a.x); u.h[1] = f2bf(a.y); u.h[2] = f2bf(a.z); u.h[3] = f2bf(a.w);
  u.h[4] = f2bf(b.x); u.h[5] = f2bf(b.y); u.h[6] = f2bf(b.z); u.h[7] = f2bf(b.w);
  return u.q;
}

// async global->LDS, 16B per lane; lds dst is wave-uniform base + lane*16
__device__ __forceinline__ void gload16(const u16* g, u16* l) {
  __builtin_amdgcn_global_load_lds(
      (const __attribute__((address_space(1))) u32*)g,
      (__attribute__((address_space(3))) u32*)l, 16, 0, 0);
}

// memory-fenced raw barrier: fences pin LDS/VMEM ops to their phase; barrier
// itself is NoMem in LLVM so both sides need the fence.
#define BARF() do { asm volatile("" ::: "memory"); \
                    __builtin_amdgcn_s_barrier();  \
                    asm volatile("" ::: "memory"); } while (0)

// ---------------------------------------------------------------------------
// 256x256-tile bf16 MFMA GEMM, 4-PHASE x 16-MFMA schedule (round-5 rebalance
// of the verified round-4 8-phase kernel: same reads, same staging, HALF the
// barriers, 2x MFMA per barrier -> fixed per-phase cost (ds_read latency +
// barrier sync ~300cy) amortized over 620cy of matrix-pipe work per SIMD).
// BK=64 K-tile, 8 waves (512 thr, 2Mx4N), wave tile 128x64, acc[8][4].
// LDS [2 buf][2 k-half][256][32] u16 = 128 KB. Verified swizzle pair:
// stage col pre-swizzled  scol = ((l&3)^((l>>3)&3))*8 ; read at
// su = (quad^((lr>>1)&3))*8  -> 2-way bank access, measured 0 conflicts.
// Phase = (khalf, ihalf): B-frags (4) read once per khalf, held 2 phases;
// A-frags (4) read per phase; 16 MFMA per phase. Stage: 4 chunks at p0
// (next-tile k0), 4 at p2 (next-tile k1). COUNTED vmcnt(4) at p1/p3 before
// their publishing barriers (retires exactly the chunk group needed 2 phases
// later; never drains in-loop; loads in flight ~3 phases >> HBM latency).
// Race trace (steady): p1.vmcnt(4) retires THIS tile's k1 (issued t-1.p2)
// before p2 reads; p3.vmcnt(4) retires NEXT tile's k0 (issued t.p0) before
// t+1.p0 reads. Buffer writes always target nb != cur.
// Grid: 64 M-blocks x (N/256), groups of 16 M-blocks (A-sharers same XCD).
// C = A(MxK, lda) * W(NxK, ldb)^T, fused epilogues:
// MODE 0: +bias, store bf16               (qkv)
// MODE 1: +bias +aux0(x f32), store f32   (out_proj -> x1 in d_out)
// MODE 3: outF += 0.1*(acc + gb)          (adapter up -> y into d_out)
// MODE 4: +bias, QuickGELU, bf16          (c_fc -> h2)
// MODE 5: outF += acc (+bias if given)    (c_proj into d_out)
// ---------------------------------------------------------------------------
template <int MODE>
__global__ __launch_bounds__(512, 2) void gemm256_k(
    const u16* __restrict__ A, int lda,
    const u16* __restrict__ W, int ldb,
    const float* __restrict__ bias, const float* __restrict__ aux0,
    float* __restrict__ outF, u16* __restrict__ outB, int N, int K)
{
  __shared__ u16 As[2][2][8192];   // [buf][khalf][256 rows x 32 cols]
  __shared__ u16 Bs[2][2][8192];
  const int tid = threadIdx.x;
  const int nxb = N >> 8;
  const int gsz = nxb << 4;               // 16 M-blocks per group
  const int g = blockIdx.x / gsz;
  const int rem = blockIdx.x - g * gsz;
  const int m0 = ((g << 4) + (rem & 15)) * 256;
  const int n0 = (rem >> 4) * 256;
  const int w = tid >> 6, lane = tid & 63, lr = lane & 15, quad = lane >> 4;
  const int wr = (w >> 2) * 128, wc = (w & 3) * 64;

  f32x4 acc[8][4];
  #pragma unroll
  for (int i = 0; i < 8; i++)
    #pragma unroll
    for (int j = 0; j < 4; j++)
      #pragma unroll
      for (int r = 0; r < 4; r++) acc[i][j][r] = 0.f;

  // staging addresses (verified round 3/4)
  const int sr = w * 16 + (lane >> 2);
  const int scol = ((lane & 3) ^ ((lane >> 3) & 3)) * 8;
  const u16* gA0 = A + (long)(m0 + sr) * lda + scol;
  const u16* gA1 = gA0 + (long)128 * lda;
  const u16* gB0 = W + (long)(n0 + sr) * ldb + scol;
  const u16* gB1 = gB0 + (long)128 * ldb;
  const int lo = w << 9;                  // wave-uniform LDS base (u16)
  const int su = (quad ^ ((lr >> 1) & 3)) * 8;   // read-side swizzled slot

  auto rdA = [&](bf16x8* af, const u16* tile, int ih) {
    #pragma unroll
    for (int i2 = 0; i2 < 4; i2++)
      af[i2] = *(const bf16x8*)&tile[(wr + ih * 64 + i2 * 16 + lr) * 32 + su];
  };
  auto rdB4 = [&](bf16x8* bb, const u16* tile) {
    #pragma unroll
    for (int j = 0; j < 4; j++)
      bb[j] = *(const bf16x8*)&tile[(wc + j * 16 + lr) * 32 + su];
  };
  auto mm16 = [&](int ih, bf16x8* af, bf16x8* bb) {
    __builtin_amdgcn_s_setprio(1);
    #pragma unroll
    for (int i2 = 0; i2 < 4; i2++)
      #pragma unroll
      for (int j = 0; j < 4; j++)
        acc[ih * 4 + i2][j] = MFMA16(af[i2], bb[j], acc[ih * 4 + i2][j]);
    __builtin_amdgcn_s_setprio(0);
  };

  const int nt = K >> 6;                  // K-tiles of 64; >= 8 at all sites

  // prologue: stage K-tile 0 (4 chunks, 8 loads/wave), drain, publish
  gload16(gA0,      As[0][0] + lo); gload16(gA1,      As[0][0] + 4096 + lo);
  gload16(gB0,      Bs[0][0] + lo); gload16(gB1,      Bs[0][0] + 4096 + lo);
  gload16(gA0 + 32, As[0][1] + lo); gload16(gA1 + 32, As[0][1] + 4096 + lo);
  gload16(gB0 + 32, Bs[0][1] + lo); gload16(gB1 + 32, Bs[0][1] + 4096 + lo);
  asm volatile("s_waitcnt vmcnt(0)" ::: "memory");
  __syncthreads();

  for (int t = 0; t < nt; ++t) {
    const int cur = t & 1, nb = cur ^ 1;
    const bool more = (t + 1) < nt;
    const long kb = (long)(t + 1) * 64;
    const u16* A0 = As[cur][0]; const u16* A1 = As[cur][1];
    const u16* B0 = Bs[cur][0]; const u16* B1 = Bs[cur][1];
    bf16x8 af[4], bb[4];
    // ---- p0: (k0, ih0) ----
    rdB4(bb, B0); rdA(af, A0, 0);
    if (more) {
      gload16(gA0 + kb, As[nb][0] + lo);
      gload16(gA1 + kb, As[nb][0] + 4096 + lo);
      gload16(gB0 + kb, Bs[nb][0] + lo);
      gload16(gB1 + kb, Bs[nb][0] + 4096 + lo);
    }
    BARF(); mm16(0, af, bb);
    // ---- p1: (k0, ih1) ----  vmcnt retires THIS tile's k1 chunks
    rdA(af, A0, 1);
    if (more) asm volatile("s_waitcnt vmcnt(4)" ::: "memory");
    else      asm volatile("s_waitcnt vmcnt(0)" ::: "memory");
    BARF(); mm16(1, af, bb);
    // ---- p2: (k1, ih0) ----
    rdB4(bb, B1); rdA(af, A1, 0);
    if (more) {
      gload16(gA0 + kb + 32, As[nb][1] + lo);
      gload16(gA1 + kb + 32, As[nb][1] + 4096 + lo);
      gload16(gB0 + kb + 32, Bs[nb][1] + lo);
      gload16(gB1 + kb + 32, Bs[nb][1] + 4096 + lo);
    }
    BARF(); mm16(0, af, bb);
    // ---- p3: (k1, ih1) ----  vmcnt retires NEXT tile's k0 chunks
    rdA(af, A1, 1);
    if (more) asm volatile("s_waitcnt vmcnt(4)" ::: "memory");
    BARF(); mm16(1, af, bb);
  }

  #pragma unroll
  for (int i = 0; i < 8; i++) {
    #pragma unroll
    for (int j = 0; j < 4; j++) {
      #pragma unroll
      for (int r = 0; r < 4; r++) {
        const int gm = m0 + wr + i * 16 + quad * 4 + r;
        const int gn = n0 + wc + j * 16 + lr;
        const long oidx = (long)gm * N + gn;
        float v = acc[i][j][r];
        if constexpr (MODE == 0) {
          v += bias[gn];
          outB[oidx] = f2bf(v);
        } else if constexpr (MODE == 1) {
          v += bias[gn] + aux0[oidx];
          outF[oidx] = v;
        } else if constexpr (MODE == 3) {
          outF[oidx] += 0.1f * (v + aux0[(gm & 63) * 1024 + gn]);
        } else if constexpr (MODE == 4) {
          v += bias[gn];
          float e = __expf(-1.702f * v);
          v = v * __builtin_amdgcn_rcpf(1.f + e);
          outB[oidx] = f2bf(v);
        } else {
          if (bias) v += bias[gn];
          outF[oidx] += v;
        }
      }
    }
  }
}

// ---------------------------------------------------------------------------
// Adapter-down GEMM (proven round-1/2 path): 128x128 tile, A f32 convert-in-
// staging, relu + gate epilogue. Small (N=512, K=1024) — not worth porting.
// ---------------------------------------------------------------------------
__global__ __launch_bounds__(256) void gemm_down_k(
    const float* __restrict__ Af, int lda,
    const u16* __restrict__ W, int ldb,
    const float* __restrict__ bias, const float* __restrict__ gates,
    u16* __restrict__ outB, int N, int K)
{
  __shared__ u16 As[2][128 * 32];
  __shared__ u16 Bs[2][128 * 32];
  const int tid = threadIdx.x;
  const int nxb = gridDim.x >> 7;
  const int gsz = nxb << 5;
  const int g = blockIdx.x / gsz;
  const int rem = blockIdx.x - g * gsz;
  const int m0 = ((g << 5) + (rem & 31)) * 128;
  const int n0 = (rem >> 5) * 128;
  const int w = tid >> 6, lane = tid & 63, lr = lane & 15, quad = lane >> 4;
  const int wm = (w >> 1) * 64, wn = (w & 1) * 64;

  f32x4 acc[4][4];
  #pragma unroll
  for (int i = 0; i < 4; i++)
    #pragma unroll
    for (int j = 0; j < 4; j++)
      #pragma unroll
      for (int r = 0; r < 4; r++) acc[i][j][r] = 0.f;

  const int srow = w * 32 + (lane >> 2);
  const int scol = (lane & 3) * 8;
  const u16* gB0 = W + (long)(n0 + srow) * ldb + scol;
  const u16* gB1 = gB0 + (long)16 * ldb;
  const int lo = w * 1024;
  const int r0 = tid >> 2, ch0 = (tid & 3) * 8;
  const float* F1 = Af + (long)(m0 + r0) * lda + ch0;
  const float* F2 = Af + (long)(m0 + r0 + 64) * lda + ch0;

  int cur = 0;
  {
    float4 p0 = *(const float4*)(F1);
    float4 p1 = *(const float4*)(F1 + 4);
    float4 q0 = *(const float4*)(F2);
    float4 q1 = *(const float4*)(F2 + 4);
    gload16(gB0, &Bs[0][lo]);
    gload16(gB1, &Bs[0][lo + 512]);
    *(uint4*)&As[0][r0 * 32 + ch0] = cvt8(p0, p1);
    *(uint4*)&As[0][(r0 + 64) * 32 + ch0] = cvt8(q0, q1);
  }
  __syncthreads();
  for (int k0 = 0; k0 < K; k0 += 32) {
    const int kn = k0 + 32;
    const bool more = kn < K;
    float4 p0, p1, q0, q1;
    if (more) {
      p0 = *(const float4*)(F1 + kn);
      p1 = *(const float4*)(F1 + kn + 4);
      q0 = *(const float4*)(F2 + kn);
      q1 = *(const float4*)(F2 + kn + 4);
      gload16(gB0 + kn, &Bs[cur ^ 1][lo]);
      gload16(gB1 + kn, &Bs[cur ^ 1][lo + 512]);
    }
    bf16x8 bfr[4];
    #pragma unroll
    for (int j = 0; j < 4; j++)
      bfr[j] = *(const bf16x8*)&Bs[cur][(wn + j * 16 + lr) * 32 + quad * 8];
    #pragma unroll
    for (int i = 0; i < 4; i++) {
      bf16x8 af = *(const bf16x8*)&As[cur][(wm + i * 16 + lr) * 32 + quad * 8];
      #pragma unroll
      for (int j = 0; j < 4; j++)
        acc[i][j] = MFMA16(af, bfr[j], acc[i][j]);
    }
    if (more) {
      *(uint4*)&As[cur ^ 1][r0 * 32 + ch0] = cvt8(p0, p1);
      *(uint4*)&As[cur ^ 1][(r0 + 64) * 32 + ch0] = cvt8(q0, q1);
    }
    __syncthreads();
    cur ^= 1;
  }

  #pragma unroll
  for (int i = 0; i < 4; i++) {
    #pragma unroll
    for (int j = 0; j < 4; j++) {
      #pragma unroll
      for (int r = 0; r < 4; r++) {
        const int gm = m0 + wm + i * 16 + quad * 4 + r;
        const int gn = n0 + wn + j * 16 + lr;
        float v = acc[i][j][r] + bias[gn];
        v = fmaxf(v, 0.f);
        float g2 = gates[(gm & 63) * 8 + (gn >> 6)];
        outB[(long)gm * N + gn] = f2bf(v * g2);
      }
    }
  }
}

// ---------------------------------------------------------------------------
// Fused attention per (b,h): S=QK^T/8 -> softmax -> P*V; O overwrites q-slot.
// qkv: [tok=l*64+b][3072], q@+0, k@+1024, v@+2048, col h*64+d. LDS ~51KB.
// ---------------------------------------------------------------------------
__global__ __launch_bounds__(256) void attn_k(u16* __restrict__ qkv)
{
  __shared__ u16 Vt[64 * 264];
  __shared__ u16 Ps[32 * 264];
  __shared__ float rowstat[64];
  float* red = (float*)Ps;  // red's lifetime ends before Ps is written
  const int bh = blockIdx.x, b = bh >> 4, h = bh & 15;
  const int tid = threadIdx.x, w = tid >> 6, lane = tid & 63;
  const int lr = lane & 15, quad = lane >> 4;
  const long base = (long)b * 3072 + h * 64;

  for (int c = tid; c < 2048; c += 256) {
    int m = c >> 3, ch = (c & 7) * 8;
    uint4 vv = *(const uint4*)(qkv + (long)m * 196608 + base + 2048 + ch);
    const u16* s = (const u16*)&vv;
    #pragma unroll
    for (int t = 0; t < 8; t++) Vt[(ch + t) * 264 + m] = s[t];
  }
  __syncthreads();

  for (int qb = 0; qb < 4; qb++) {
    f32x4 acc[4][4];
    #pragma unroll
    for (int i = 0; i < 4; i++)
      #pragma unroll
      for (int j = 0; j < 4; j++)
        #pragma unroll
        for (int r = 0; r < 4; r++) acc[i][j][r] = 0.f;

    #pragma unroll
    for (int ks = 0; ks < 2; ks++) {
      bf16x8 bfr[4];
      #pragma unroll
      for (int j = 0; j < 4; j++) {
        int key = w * 64 + j * 16 + lr;
        bfr[j] = *(const bf16x8*)(qkv + (long)key * 196608 + base + 1024 + ks * 32 + quad * 8);
      }
      #pragma unroll
      for (int i = 0; i < 4; i++) {
        int gq = qb * 64 + i * 16 + lr;
        bf16x8 af = *(const bf16x8*)(qkv + (long)gq * 196608 + base + ks * 32 + quad * 8);
        #pragma unroll
        for (int j = 0; j < 4; j++)
          acc[i][j] = MFMA16(af, bfr[j], acc[i][j]);
      }
    }

    #pragma unroll
    for (int i = 0; i < 4; i++) {
      #pragma unroll
      for (int r = 0; r < 4; r++) {
        float m = -1e30f;
        #pragma unroll
        for (int j = 0; j < 4; j++) {
          float s = acc[i][j][r] * 0.125f;
          acc[i][j][r] = s;
          m = fmaxf(m, s);
        }
        #pragma unroll
        for (int off = 1; off < 16; off <<= 1) m = fmaxf(m, __shfl_xor(m, off));
        if (lr == 0) red[w * 64 + i * 16 + quad * 4 + r] = m;
      }
    }
    __syncthreads();
    if (tid < 64)
      rowstat[tid] = fmaxf(fmaxf(red[tid], red[64 + tid]),
                           fmaxf(red[128 + tid], red[192 + tid]));
    __syncthreads();

    #pragma unroll
    for (int i = 0; i < 4; i++) {
      #pragma unroll
      for (int r = 0; r < 4; r++) {
        float rm = rowstat[i * 16 + quad * 4 + r];
        float s = 0.f;
        #pragma unroll
        for (int j = 0; j < 4; j++) {
          float e = __expf(acc[i][j][r] - rm);
          acc[i][j][r] = e;
          s += e;
        }
        #pragma unroll
        for (int off = 1; off < 16; off <<= 1) s += __shfl_xor(s, off);
        if (lr == 0) red[w * 64 + i * 16 + quad * 4 + r] = s;
      }
    }
    __syncthreads();
    if (tid < 64)
      rowstat[tid] = red[tid] + red[64 + tid] + red[128 + tid] + red[192 + tid];
    __syncthreads();

    #pragma unroll
    for (int hf = 0; hf < 2; hf++) {
      #pragma unroll
      for (int ii = 0; ii < 2; ii++) {
        int i = hf * 2 + ii;
        #pragma unroll
        for (int r = 0; r < 4; r++) {
          int row = i * 16 + quad * 4 + r;
          float inv = 1.f / rowstat[row];
          #pragma unroll
          for (int j = 0; j < 4; j++)
            Ps[(row - hf * 32) * 264 + w * 64 + j * 16 + lr] =
                f2bf(acc[i][j][r] * inv);
        }
      }
      __syncthreads();
      f32x4 o[2];
      #pragma unroll
      for (int j2 = 0; j2 < 2; j2++)
        #pragma unroll
        for (int r = 0; r < 4; r++) o[j2][r] = 0.f;
      #pragma unroll
      for (int ks = 0; ks < 8; ks++) {
        bf16x8 af = *(const bf16x8*)&Ps[((w >> 1) * 16 + lr) * 264 + ks * 32 + quad * 8];
        #pragma unroll
        for (int j2 = 0; j2 < 2; j2++) {
          int j = (w & 1) * 2 + j2;
          bf16x8 bv = *(const bf16x8*)&Vt[(j * 16 + lr) * 264 + ks * 32 + quad * 8];
          o[j2] = MFMA16(af, bv, o[j2]);
        }
      }
      int l0 = qb * 64 + hf * 32 + (w >> 1) * 16 + quad * 4;
      #pragma unroll
      for (int j2 = 0; j2 < 2; j2++) {
        int j = (w & 1) * 2 + j2;
        #pragma unroll
        for (int r = 0; r < 4; r++)
          qkv[(long)(l0 + r) * 196608 + base + j * 16 + lr] = f2bf(o[j2][r]);
      }
      __syncthreads();
    }
  }
}

// --------------------------- LayerNorm (f32 -> bf16) -----------------------
__global__ __launch_bounds__(256) void ln_k(const float* __restrict__ x,
                                            const float* __restrict__ wt,
                                            const float* __restrict__ bs,
                                            u16* __restrict__ out)
{
  const int tok = blockIdx.x * 4 + (threadIdx.x >> 6);
  const int lane = threadIdx.x & 63;
  const float* xp = x + (long)tok * 1024;
  float4 v[4];
  float s = 0.f, s2 = 0.f;
  #pragma unroll
  for (int t = 0; t < 4; t++) {
    v[t] = *(const float4*)(xp + t * 256 + lane * 4);
    s += v[t].x + v[t].y + v[t].z + v[t].w;
    s2 += v[t].x * v[t].x + v[t].y * v[t].y + v[t].z * v[t].z + v[t].w * v[t].w;
  }
  #pragma unroll
  for (int off = 32; off >= 1; off >>= 1) {
    s += __shfl_xor(s, off);
    s2 += __shfl_xor(s2, off);
  }
  const float m = s * (1.f / 1024.f);
  const float rstd = rsqrtf(s2 * (1.f / 1024.f) - m * m + 1e-5f);
  u16* op = out + (long)tok * 1024;
  #pragma unroll
  for (int t = 0; t < 4; t++) {
    int d = t * 256 + lane * 4;
    float4 wv = *(const float4*)(wt + d);
    float4 bv = *(const float4*)(bs + d);
    union { u16 h[4]; uint2 q; } o;
    o.h[0] = f2bf((v[t].x - m) * rstd * wv.x + bv.x);
    o.h[1] = f2bf((v[t].y - m) * rstd * wv.y + bv.y);
    o.h[2] = f2bf((v[t].z - m) * rstd * wv.z + bv.z);
    o.h[3] = f2bf((v[t].w - m) * rstd * wv.w + bv.w);
    *(uint2*)(op + d) = o.q;
  }
}

// --------------------------- weight converts -------------------------------
__global__ void cvtk(const float* __restrict__ src, u16* __restrict__ dst, int n4)
{
  int i = blockIdx.x * 256 + threadIdx.x;
  if (i >= n4) return;
  float4 v = ((const float4*)src)[i];
  union { u16 h[4]; uint2 q; } o;
  o.h[0] = f2bf(v.x); o.h[1] = f2bf(v.y); o.h[2] = f2bf(v.z); o.h[3] = f2bf(v.w);
  ((uint2*)dst)[i] = o.q;
}

// dst[d*512 + e*64 + r] = up_w[(e*1024 + d)*64 + r]   (up_w is (E,D,R))
__global__ void wupk(const float* __restrict__ up_w, u16* __restrict__ dst)
{
  int i = blockIdx.x * 256 + threadIdx.x;  // 524288
  int r = i & 63, e = (i >> 6) & 7, d = i >> 9;
  dst[i] = f2bf(up_w[(e * 1024 + d) * 64 + r]);
}

// --------------------------- gating ----------------------------------------
__global__ __launch_bounds__(256) void gate_k(const float* __restrict__ x1,
                                              const float* __restrict__ wg,
                                              float* __restrict__ gates)
{
  const int wv = threadIdx.x >> 6, lane = threadIdx.x & 63;
  const int b = blockIdx.x * 4 + wv;
  const float* xp = x1 + (long)b * 1024;
  float lg[8];
  #pragma unroll
  for (int e = 0; e < 8; e++) lg[e] = 0.f;
  for (int i = 0; i < 16; i++) {
    int d = i * 64 + lane;
    float xv = xp[d];
    #pragma unroll
    for (int e = 0; e < 8; e++) lg[e] += xv * wg[d * 8 + e];
  }
  #pragma unroll
  for (int e = 0; e < 8; e++)
    #pragma unroll
    for (int off = 32; off >= 1; off >>= 1) lg[e] += __shfl_xor(lg[e], off);
  if (lane == 0) {
    int e1 = 0; float v1 = lg[0];
    #pragma unroll
    for (int e = 1; e < 8; e++) if (lg[e] > v1) { v1 = lg[e]; e1 = e; }
    int e2 = -1; float v2 = -1e30f;
    #pragma unroll
    for (int e = 0; e < 8; e++) if (e != e1 && lg[e] > v2) { v2 = lg[e]; e2 = e; }
    float ex = __expf(v2 - v1);
    float inv = 1.f / (1.f + ex);
    #pragma unroll
    for (int e = 0; e < 8; e++)
      gates[b * 8 + e] = (e == e1) ? inv : ((e == e2) ? ex * inv : 0.f);
  }
}

__global__ void moe_loss_k(const float* __restrict__ gates, float* __restrict__ out)
{
  if (threadIdx.x != 0) return;
  float imp[8], ld[8];
  for (int e = 0; e < 8; e++) { imp[e] = 0.f; ld[e] = 0.f; }
  for (int b = 0; b < 64; b++)
    for (int e = 0; e < 8; e++) {
      float g = gates[b * 8 + e];
      imp[e] += g;
      if (g > 0.f) ld[e] += 1.f;
    }
  float mi = 0.f, ml = 0.f;
  for (int e = 0; e < 8; e++) { mi += imp[e]; ml += ld[e]; }
  mi *= 0.125f; ml *= 0.125f;
  float vi = 0.f, vl = 0.f;
  for (int e = 0; e < 8; e++) {
    float a = imp[e] - mi; vi += a * a;
    float c = ld[e] - ml; vl += c * c;
  }
  vi *= (1.f / 7.f); vl *= (1.f / 7.f);
  out[0] = 0.01f * (vi / (mi * mi + 1e-10f) + vl / (ml * ml + 1e-10f));
}

// gb[b][d] = sum_e gates[b,e] * up_b[e,d]
__global__ __launch_bounds__(256) void gb_k(const float* __restrict__ gates,
                                            const float* __restrict__ up_b,
                                            float* __restrict__ gb)
{
  int b = blockIdx.x, d0 = threadIdx.x * 4;
  float g[8];
  #pragma unroll
  for (int e = 0; e < 8; e++) g[e] = gates[b * 8 + e];
  float s0 = 0, s1 = 0, s2 = 0, s3 = 0;
  #pragma unroll
  for (int e = 0; e < 8; e++) {
    float4 u = *(const float4*)(up_b + e * 1024 + d0);
    s0 += g[e] * u.x; s1 += g[e] * u.y; s2 += g[e] * u.z; s3 += g[e] * u.w;
  }
  float4 r; r.x = s0; r.y = s1; r.z = s2; r.w = s3;
  *(float4*)(gb + b * 1024 + d0) = r;
}

// ---------------------------------------------------------------------------
extern "C" void kernel_launch(void* const* d_in, const int* in_sizes, int n_in,
                              void* d_out, int out_size, void* d_ws, size_t ws_size,
                              hipStream_t stream)
{
  (void)in_sizes; (void)n_in; (void)out_size;
  const float* x      = (const float*)d_in[0];
  const float* ln1_w  = (const float*)d_in[1];
  const float* ln1_b  = (const float*)d_in[2];
  const float* in_w   = (const float*)d_in[3];
  const float* in_b   = (const float*)d_in[4];
  const float* out_w  = (const float*)d_in[5];
  const float* out_b  = (const float*)d_in[6];
  const float* ln2_w  = (const float*)d_in[7];
  const float* ln2_b  = (const float*)d_in[8];
  const float* fc_w   = (const float*)d_in[9];
  const float* fc_b   = (const float*)d_in[10];
  const float* pj_w   = (const float*)d_in[11];
  const float* pj_b   = (const float*)d_in[12];
  const float* w_gate = (const float*)d_in[13];
  const float* down_w = (const float*)d_in[14];
  const float* down_b = (const float*)d_in[15];
  const float* up_w   = (const float*)d_in[16];
  const float* up_b   = (const float*)d_in[17];
  float* out = (float*)d_out;
  char* ws = (char*)d_ws;

  // ws layout (base footprint ~115 MB, proven), lifetime-aliased
  u16* wb_in   = (u16*)(ws + 0);          // 6 MB   (dead after qkv gemm)
  u16* wb_out  = (u16*)(ws + 6291456);    // 2 MB   (dead after out_proj)
  u16* wb_down = (u16*)(ws + 8388608);    // 1 MB
  u16* wb_up   = (u16*)(ws + 9437184);    // 1 MB
  u16* wb_fc   = (u16*)(ws + 0);          // 8 MB   (aliases in/out, converted late)
  u16* wb_pj   = (u16*)(ws + 10485760);   // 8 MB
  float* gates = (float*)(ws + 19005440); // 2 KB
  float* gb    = (float*)(ws + 19007488); // 256 KB
  u16* qkv     = (u16*)(ws + 19269632);   // 96 MB  (dead after out_proj)
  u16* xln2    = (u16*)(ws + 19269632);   // 32 MB  (alias qkv[0:32M])
  u16* hg      = (u16*)(ws + 52824064);   // 16 MB  (alias qkv[32M:48M])
  u16* h2      = (u16*)(ws + 69601280);   // 32 MB chunked / 128 MB if ws allows
  // xln (LN1 output, bf16) lives in d_out until out_proj overwrites it
  u16* xln = (u16*)d_out;

  const bool big = ws_size >= (size_t)203819008;  // 69601280 + 128 MB

  // phase-1 weight converts
  cvtk<<<3072, 256, 0, stream>>>(in_w, wb_in, 786432);
  cvtk<<<1024, 256, 0, stream>>>(out_w, wb_out, 262144);
  cvtk<<<512, 256, 0, stream>>>(down_w, wb_down, 131072);
  wupk<<<2048, 256, 0, stream>>>(up_w, wb_up);

  // LN1 -> xln (bf16, in d_out); qkv = xln @ in_w^T + in_b
  ln_k<<<4096, 256, 0, stream>>>(x, ln1_w, ln1_b, xln);
  gemm256_k<0><<<64 * 12, 512, 0, stream>>>(
      xln, 1024, wb_in, 1024, in_b, nullptr, nullptr, qkv, 3072, 1024);

  // fused attention; O overwrites q-slot of qkv
  attn_k<<<1024, 256, 0, stream>>>(qkv);

  // x1 = O @ out_w^T + out_b + x  -> d_out (f32)
  gemm256_k<1><<<64 * 4, 512, 0, stream>>>(
      qkv, 3072, wb_out, 1024, out_b, x, out, nullptr, 1024, 1024);

  // gating on x1 rows 0..63 (token 0 of each sequence)
  gate_k<<<16, 256, 0, stream>>>(out, w_gate, gates);
  moe_loss_k<<<1, 64, 0, stream>>>(gates, out + 16777216);
  gb_k<<<64, 256, 0, stream>>>(gates, up_b, gb);

  // LN2 must see pure x1 (before y accumulates into d_out)
  ln_k<<<4096, 256, 0, stream>>>(out, ln2_w, ln2_b, xln2);

  // adapter: down (relu, *gate) from f32 x1; up accumulates y into d_out
  gemm_down_k<<<4 * 128, 256, 0, stream>>>(
      out, 1024, wb_down, 1024, down_b, gates, hg, 512, 1024);
  gemm256_k<3><<<64 * 4, 512, 0, stream>>>(
      hg, 512, wb_up, 512, nullptr, gb, out, nullptr, 1024, 512);

  // phase-2 weight converts (overwrite dead phase-1 buffers)
  cvtk<<<4096, 256, 0, stream>>>(fc_w, wb_fc, 1048576);
  cvtk<<<4096, 256, 0, stream>>>(pj_w, wb_pj, 1048576);

  if (big) {
    // single-shot MLP: h2 = QuickGELU(xln2 @ fc_w^T + fc_b); out += h2 @ pj_w^T + pj_b
    gemm256_k<4><<<64 * 16, 512, 0, stream>>>(
        xln2, 1024, wb_fc, 1024, fc_b, nullptr, nullptr, h2, 4096, 1024);
    gemm256_k<5><<<64 * 4, 512, 0, stream>>>(
        h2, 4096, wb_pj, 4096, pj_b, nullptr, out, nullptr, 1024, 4096);
  } else {
    // 4 K-chunks (proven 115 MB footprint)
    for (int c = 0; c < 4; c++) {
      gemm256_k<4><<<64 * 4, 512, 0, stream>>>(
          xln2, 1024, wb_fc + (long)c * 1048576, 1024, fc_b + c * 1024,
          nullptr, nullptr, h2, 1024, 1024);
      gemm256_k<5><<<64 * 4, 512, 0, stream>>>(
          h2, 1024, wb_pj + c * 1024, 4096, (c == 0) ? pj_b : nullptr,
          nullptr, out, nullptr, 1024, 1024);
    }
  }
}